// Round 2
// baseline (283.059 us; speedup 1.0000x reference)
//
#include <hip/hip_runtime.h>

typedef unsigned short u16;
typedef float f32x4 __attribute__((ext_vector_type(4)));
typedef short s16x8 __attribute__((ext_vector_type(8)));

#define B_ 2
#define N_ 2048
#define C_ 1024
#define H_ 16
#define BN_ (B_*N_)   // 4096 rows

// ---------- helpers ----------
__device__ __forceinline__ u16 f2bf(float f) {
  union { float f; unsigned u; } c; c.f = f;
  unsigned u = c.u;
  u = (u + 0x7fffu + ((u >> 16) & 1u)) >> 16;   // RNE
  return (u16)u;
}
__device__ __forceinline__ float bf2f(u16 h) {
  union { unsigned u; float f; } c; c.u = ((unsigned)h) << 16;
  return c.f;
}
__device__ __forceinline__ void gload16(const u16* g, u16* l) {
  __builtin_amdgcn_global_load_lds(
      (const __attribute__((address_space(1))) unsigned*)g,
      (__attribute__((address_space(3))) unsigned*)l, 16, 0, 0);
}

// ---------- fp32 -> bf16 cast (vectorized) ----------
__global__ __launch_bounds__(256) void k_cast_bf16(const float* __restrict__ x,
                                                   u16* __restrict__ o, int n4) {
  int i = blockIdx.x * blockDim.x + threadIdx.x;
  if (i >= n4) return;
  float4 v = ((const float4*)x)[i];
  ushort4 r;
  r.x = f2bf(v.x); r.y = f2bf(v.y); r.z = f2bf(v.z); r.w = f2bf(v.w);
  ((ushort4*)o)[i] = r;
}

// ---------- fp32 [R][C] -> bf16 [C][R] transpose+cast ----------
__global__ __launch_bounds__(256) void k_transpose_cast(const float* __restrict__ W,
                                                        u16* __restrict__ Wt,
                                                        int R, int Cc) {
  __shared__ float t[32][33];
  int tx = threadIdx.x, ty = threadIdx.y;
  int c0 = blockIdx.x * 32, r0 = blockIdx.y * 32;
#pragma unroll
  for (int i = 0; i < 4; ++i)
    t[ty + i * 8][tx] = W[(long)(r0 + ty + i * 8) * Cc + c0 + tx];
  __syncthreads();
#pragma unroll
  for (int i = 0; i < 4; ++i)
    Wt[(long)(c0 + ty + i * 8) * R + r0 + tx] = f2bf(t[tx][ty + i * 8]);
}

// ---------- GEMM: C[M][N] = A[M][K](bf16) * Bt[N][K](bf16)^T  (m97-style) ----------
// MODE 0: output bf16, no bias.  MODE 1: output fp32 + bias.
template <int MODE>
__global__ __launch_bounds__(256) void k_gemm_bt(const u16* __restrict__ A,
                                                 const u16* __restrict__ Bt,
                                                 void* __restrict__ Cout,
                                                 const float* __restrict__ bias,
                                                 int M, int N, int K) {
  __shared__ u16 a_t[128 * 64];
  __shared__ u16 b_t[128 * 64];
  int tid = threadIdx.x;
  int w = tid >> 6, l = tid & 63;
  int l15 = l & 15, lhi = l >> 4;
  int wm = w >> 1, wn = w & 1;
  int rowA = l >> 3, colA = (l & 7) * 8;
  const u16* Ab = A + (long)blockIdx.y * 128 * K;
  const u16* Bb = Bt + (long)blockIdx.x * 128 * K;
  f32x4 acc[4][4];
#pragma unroll
  for (int m = 0; m < 4; ++m)
#pragma unroll
    for (int n = 0; n < 4; ++n)
      acc[m][n] = (f32x4){0.f, 0.f, 0.f, 0.f};

  for (int k0 = 0; k0 < K; k0 += 64) {
#pragma unroll
    for (int i = 0; i < 4; ++i) {
      int ci = i * 4 + w;
      gload16(Ab + (long)(ci * 8 + rowA) * K + k0 + colA, &a_t[ci * 8 * 64]);
      gload16(Bb + (long)(ci * 8 + rowA) * K + k0 + colA, &b_t[ci * 8 * 64]);
    }
    __syncthreads();
#pragma unroll
    for (int kk = 0; kk < 2; ++kk) {
      s16x8 af[4], bfr[4];
#pragma unroll
      for (int m = 0; m < 4; ++m)
        af[m] = *(const s16x8*)&a_t[(wm * 64 + m * 16 + l15) * 64 + kk * 32 + lhi * 8];
#pragma unroll
      for (int n = 0; n < 4; ++n)
        bfr[n] = *(const s16x8*)&b_t[(wn * 64 + n * 16 + l15) * 64 + kk * 32 + lhi * 8];
#pragma unroll
      for (int m = 0; m < 4; ++m)
#pragma unroll
        for (int n = 0; n < 4; ++n)
          acc[m][n] = __builtin_amdgcn_mfma_f32_16x16x32_bf16(af[m], bfr[n], acc[m][n], 0, 0, 0);
    }
    __syncthreads();
  }
#pragma unroll
  for (int m = 0; m < 4; ++m) {
#pragma unroll
    for (int n = 0; n < 4; ++n) {
      int col = blockIdx.x * 128 + wn * 64 + n * 16 + l15;
#pragma unroll
      for (int r = 0; r < 4; ++r) {
        int row = blockIdx.y * 128 + wm * 64 + m * 16 + lhi * 4 + r;
        float v = acc[m][n][r];
        if (MODE == 1)
          ((float*)Cout)[(long)row * N + col] = v + bias[col];
        else
          ((u16*)Cout)[(long)row * N + col] = f2bf(v);
      }
    }
  }
}

// ---------- LayerNorm(Dh=64) on q,k + split/transpose to [B*H][N][64] ----------
// NOTE: folds the attention softmax scale (1/8) into the Q LayerNorm output
// (exact power-of-2 scale; no precision loss).
__global__ __launch_bounds__(256) void k_ln_split(const u16* __restrict__ qkvb,
                                                  const float* __restrict__ qg,
                                                  const float* __restrict__ qbeta,
                                                  const float* __restrict__ kg,
                                                  const float* __restrict__ kbeta,
                                                  u16* __restrict__ Qh,
                                                  u16* __restrict__ Kh,
                                                  u16* __restrict__ Vh) {
  int wid = threadIdx.x >> 6, l = threadIdx.x & 63;
  const long nrows = (long)BN_ * 3 * H_;  // 196608 rows of 64
  for (long row = (long)blockIdx.x * 4 + wid; row < nrows; row += (long)gridDim.x * 4) {
    float v = bf2f(qkvb[row * 64 + l]);
    int h = (int)(row & 15);
    long t1 = row >> 4;           // (b*N+n)*3 + s
    int s = (int)(t1 % 3);
    long bn = t1 / 3;             // b*N + n
    long orow = ((bn >> 11) * H_ + h) * (long)N_ + (bn & (N_ - 1));
    if (s == 2) {
      Vh[orow * 64 + l] = f2bf(v);
      continue;
    }
    float m = v;
#pragma unroll
    for (int o = 1; o < 64; o <<= 1) m += __shfl_xor(m, o);
    m *= (1.f / 64.f);
    float d = v - m;
    float va = d * d;
#pragma unroll
    for (int o = 1; o < 64; o <<= 1) va += __shfl_xor(va, o);
    va *= (1.f / 64.f);
    float rs = rsqrtf(va + 1e-6f);
    float y = (s == 0) ? 0.125f * (qg[l] * d * rs + qbeta[l])
                       : (kg[l] * d * rs + kbeta[l]);
    u16* O = (s == 0) ? Qh : Kh;
    O[orow * 64 + l] = f2bf(y);
  }
}

// ---------- V [bh][N][64] -> Vt [bh][64][N] (bf16 transpose) ----------
__global__ __launch_bounds__(512) void k_transpose_v(const u16* __restrict__ Vh,
                                                     u16* __restrict__ Vt) {
  __shared__ u16 t[64][65];
  int tx = threadIdx.x, ty = threadIdx.y;  // (64,8)
  int bh = blockIdx.y;
  int n0 = blockIdx.x * 64;
#pragma unroll
  for (int i = 0; i < 8; ++i)
    t[ty + i * 8][tx] = Vh[((long)bh * N_ + n0 + ty + i * 8) * 64 + tx];
  __syncthreads();
#pragma unroll
  for (int i = 0; i < 8; ++i)
    Vt[((long)bh * 64 + ty + i * 8) * N_ + n0 + tx] = t[tx][ty + i * 8];
}

// ---------- flash attention (T2 XOR-swizzled LDS) ----------
// Qh (pre-scaled by 1/8), Kh: [bh][N][64] bf16, Vt: [bh][64][N] bf16,
// O: [B][N][H*64] bf16.
// LDS swizzle: 16-B slot c of row r lives at physical slot (c ^ (r & 7)) for
// k_t (8 slots/row) and (c ^ (r & 15)) for v_t/p_t (16 slots/row).
// K/V are staged with global_load_lds (linear dest), so the *global source*
// column is pre-swizzled per-lane (m173 pattern, rule #21).
__global__ __launch_bounds__(256) void k_attn(const u16* __restrict__ Qh,
                                              const u16* __restrict__ Kh,
                                              const u16* __restrict__ Vt,
                                              u16* __restrict__ O) {
  __shared__ u16 k_t[128 * 64];
  __shared__ u16 v_t[64 * 128];
  __shared__ u16 p_t[128 * 128];
  int tid = threadIdx.x;
  int w = tid >> 6, l = tid & 63;
  int l15 = l & 15, lhi = l >> 4;
  int qb = blockIdx.x, bh = blockIdx.y;
  int b = bh >> 4, h = bh & 15;
  const u16* Qb = Qh + ((long)bh * N_ + qb * 128) * 64;
  const u16* Kb = Kh + (long)bh * N_ * 64;
  const u16* Vb = Vt + (long)bh * 64 * N_;

  // hoist Q fragments to registers
  s16x8 qf[2][2];
#pragma unroll
  for (int mf = 0; mf < 2; ++mf)
#pragma unroll
    for (int kk = 0; kk < 2; ++kk)
      qf[mf][kk] = *(const s16x8*)&Qb[(long)(w * 32 + mf * 16 + l15) * 64 + kk * 32 + lhi * 8];

  f32x4 acc[2][4];
#pragma unroll
  for (int mf = 0; mf < 2; ++mf)
#pragma unroll
    for (int nd = 0; nd < 4; ++nd) acc[mf][nd] = (f32x4){0.f, 0.f, 0.f, 0.f};
  float mrow[2][4], lrow[2][4];
#pragma unroll
  for (int mf = 0; mf < 2; ++mf)
#pragma unroll
    for (int r = 0; r < 4; ++r) { mrow[mf][r] = -3e38f; lrow[mf][r] = 0.f; }

  // K staging: lane l covers row (l>>3) of the 8-row stripe, physical slot (l&7).
  // logical slot = (l&7) ^ (row&7); row&7 = (l>>3)&7 since stripes are 8-aligned.
  int rowK = l >> 3;
  int colK = (((l & 7) ^ (rowK & 7)) * 8);
  // V staging: lane l covers row (l>>4) of the 4-row stripe, physical slot (l&15).
  int rowV = l >> 4;

  for (int t = 0; t < N_ / 128; ++t) {
    int kt = t * 128;
#pragma unroll
    for (int i = 0; i < 4; ++i) {
      int ci = i * 4 + w;
      gload16(Kb + (long)(kt + ci * 8 + rowK) * 64 + colK, &k_t[ci * 8 * 64]);
      int vrow = ci * 4 + rowV;
      int colV = (((l & 15) ^ (vrow & 15)) * 8);
      gload16(Vb + (long)vrow * N_ + kt + colV, &v_t[ci * 4 * 128]);
    }
    __syncthreads();

    // S = Q K^T   (Q pre-scaled by 1/8)
    f32x4 s[2][8];
#pragma unroll
    for (int mf = 0; mf < 2; ++mf)
#pragma unroll
      for (int nf = 0; nf < 8; ++nf) s[mf][nf] = (f32x4){0.f, 0.f, 0.f, 0.f};
#pragma unroll
    for (int nf = 0; nf < 8; ++nf) {
      int krow = nf * 16 + l15;
#pragma unroll
      for (int kk = 0; kk < 2; ++kk) {
        int cph = (kk * 4 + lhi) ^ (krow & 7);
        s16x8 kfrag = *(const s16x8*)&k_t[krow * 64 + cph * 8];
        s[0][nf] = __builtin_amdgcn_mfma_f32_16x16x32_bf16(qf[0][kk], kfrag, s[0][nf], 0, 0, 0);
        s[1][nf] = __builtin_amdgcn_mfma_f32_16x16x32_bf16(qf[1][kk], kfrag, s[1][nf], 0, 0, 0);
      }
    }

    // online softmax (row = mf*16 + lhi*4 + r ; col = nf*16 + l15)
#pragma unroll
    for (int mf = 0; mf < 2; ++mf) {
#pragma unroll
      for (int r = 0; r < 4; ++r) {
        float mx = -3e38f;
#pragma unroll
        for (int nf = 0; nf < 8; ++nf) mx = fmaxf(mx, s[mf][nf][r]);
#pragma unroll
        for (int o = 1; o < 16; o <<= 1) mx = fmaxf(mx, __shfl_xor(mx, o));
        float mnew = fmaxf(mrow[mf][r], mx);
        float alpha = __expf(mrow[mf][r] - mnew);
        mrow[mf][r] = mnew;
        float rsum = 0.f;
#pragma unroll
        for (int nf = 0; nf < 8; ++nf) {
          float p = __expf(s[mf][nf][r] - mnew);
          s[mf][nf][r] = p;
          rsum += p;
        }
#pragma unroll
        for (int o = 1; o < 16; o <<= 1) rsum += __shfl_xor(rsum, o);
        lrow[mf][r] = lrow[mf][r] * alpha + rsum;
#pragma unroll
        for (int nd = 0; nd < 4; ++nd) acc[mf][nd][r] *= alpha;
      }
    }

    // P -> LDS (bf16, swizzled)
#pragma unroll
    for (int mf = 0; mf < 2; ++mf) {
#pragma unroll
      for (int r = 0; r < 4; ++r) {
        int prow = w * 32 + mf * 16 + lhi * 4 + r;
        int rx = prow & 15;
#pragma unroll
        for (int nf = 0; nf < 8; ++nf) {
          int pcol = nf * 16 + l15;
          int cph = (pcol >> 3) ^ rx;
          p_t[prow * 128 + cph * 8 + (pcol & 7)] = f2bf(s[mf][nf][r]);
        }
      }
    }
    __syncthreads();  // cross-lane LDS exchange: order P-writes before P-reads

    // O += P V
#pragma unroll
    for (int kf = 0; kf < 4; ++kf) {
      s16x8 pa[2];
#pragma unroll
      for (int mf = 0; mf < 2; ++mf) {
        int prow = w * 32 + mf * 16 + l15;
        int cph = (kf * 4 + lhi) ^ (prow & 15);
        pa[mf] = *(const s16x8*)&p_t[prow * 128 + cph * 8];
      }
#pragma unroll
      for (int nd = 0; nd < 4; ++nd) {
        int vrow = nd * 16 + l15;
        int cph = (kf * 4 + lhi) ^ (vrow & 15);
        s16x8 vb = *(const s16x8*)&v_t[vrow * 128 + cph * 8];
        acc[0][nd] = __builtin_amdgcn_mfma_f32_16x16x32_bf16(pa[0], vb, acc[0][nd], 0, 0, 0);
        acc[1][nd] = __builtin_amdgcn_mfma_f32_16x16x32_bf16(pa[1], vb, acc[1][nd], 0, 0, 0);
      }
    }
    __syncthreads();
  }

  // epilogue: O[b][q][h*64+d] = acc / l
#pragma unroll
  for (int mf = 0; mf < 2; ++mf) {
#pragma unroll
    for (int r = 0; r < 4; ++r) {
      float inv = 1.f / lrow[mf][r];
      int q = qb * 128 + w * 32 + mf * 16 + lhi * 4 + r;
#pragma unroll
      for (int nd = 0; nd < 4; ++nd) {
        int d = nd * 16 + l15;
        O[((long)(b * N_ + q) * H_ + h) * 64 + d] = f2bf(acc[mf][nd][r] * inv);
      }
    }
  }
}

// ---------- launch ----------
extern "C" void kernel_launch(void* const* d_in, const int* in_sizes, int n_in,
                              void* d_out, int out_size, void* d_ws, size_t ws_size,
                              hipStream_t stream) {
  const float* x      = (const float*)d_in[0];
  const float* qkv_w  = (const float*)d_in[1];
  const float* q_g    = (const float*)d_in[2];
  const float* q_b    = (const float*)d_in[3];
  const float* k_g    = (const float*)d_in[4];
  const float* k_b    = (const float*)d_in[5];
  const float* proj_w = (const float*)d_in[6];
  const float* proj_b = (const float*)d_in[7];
  float* out = (float*)d_out;

  char* ws = (char*)d_ws;
  // byte offsets (all 256-aligned)
  u16* xb     = (u16*)(ws + 0);                       //  8 MB  [4096][1024]
  u16* wqkvT  = (u16*)(ws + 8388608);                 //  6 MB  [3072][1024]
  u16* wprojT = (u16*)(ws + 14680064);                //  2 MB  [1024][1024]
  u16* qkvb   = (u16*)(ws + 16777216);                // 24 MB  [4096][3072]
  u16* Qh     = (u16*)(ws + 41943040);                //  8 MB  [32][2048][64]
  u16* Kh     = (u16*)(ws + 50331648);                //  8 MB
  u16* Vh     = (u16*)(ws + 58720256);                //  8 MB
  u16* Vt     = (u16*)(ws + 67108864);                //  8 MB  [32][64][2048]
  u16* attnO  = xb;                                   // reuse (xb dead after QKV GEMM)

  k_cast_bf16<<<4096, 256, 0, stream>>>(x, xb, (BN_ * C_) / 4);
  k_transpose_cast<<<dim3(96, 32), dim3(32, 8), 0, stream>>>(qkv_w, wqkvT, C_, 3 * C_);
  k_transpose_cast<<<dim3(32, 32), dim3(32, 8), 0, stream>>>(proj_w, wprojT, C_, C_);
  k_gemm_bt<0><<<dim3(24, 32), 256, 0, stream>>>(xb, wqkvT, qkvb, nullptr, BN_, 3 * C_, C_);
  k_ln_split<<<2048, 256, 0, stream>>>(qkvb, q_g, q_b, k_g, k_b, Qh, Kh, Vh);
  k_transpose_v<<<dim3(32, 32), dim3(64, 8), 0, stream>>>(Vh, Vt);
  k_attn<<<dim3(16, 32), 256, 0, stream>>>(Qh, Kh, Vt, attnO);
  k_gemm_bt<1><<<dim3(8, 32), 256, 0, stream>>>(attnO, wprojT, out, proj_b, BN_, C_, C_);
}

// Round 3
// 226.166 us; speedup vs baseline: 1.2516x; 1.2516x over previous
//
#include <hip/hip_runtime.h>

typedef unsigned short u16;
typedef float f32x4 __attribute__((ext_vector_type(4)));
typedef short s16x8 __attribute__((ext_vector_type(8)));

#define B_ 2
#define N_ 2048
#define C_ 1024
#define H_ 16
#define BN_ (B_*N_)   // 4096 rows

// ---------- helpers ----------
__device__ __forceinline__ u16 f2bf(float f) {
  union { float f; unsigned u; } c; c.f = f;
  unsigned u = c.u;
  u = (u + 0x7fffu + ((u >> 16) & 1u)) >> 16;   // RNE
  return (u16)u;
}
__device__ __forceinline__ float bf2f(u16 h) {
  union { unsigned u; float f; } c; c.u = ((unsigned)h) << 16;
  return c.f;
}
__device__ __forceinline__ void gload16(const u16* g, u16* l) {
  __builtin_amdgcn_global_load_lds(
      (const __attribute__((address_space(1))) unsigned*)g,
      (__attribute__((address_space(3))) unsigned*)l, 16, 0, 0);
}

// ---------- fp32 -> bf16 cast (vectorized) ----------
__global__ __launch_bounds__(256) void k_cast_bf16(const float* __restrict__ x,
                                                   u16* __restrict__ o, int n4) {
  int i = blockIdx.x * blockDim.x + threadIdx.x;
  if (i >= n4) return;
  float4 v = ((const float4*)x)[i];
  ushort4 r;
  r.x = f2bf(v.x); r.y = f2bf(v.y); r.z = f2bf(v.z); r.w = f2bf(v.w);
  ((ushort4*)o)[i] = r;
}

// ---------- fp32 [R][C] -> bf16 [C][R] transpose+cast ----------
__global__ __launch_bounds__(256) void k_transpose_cast(const float* __restrict__ W,
                                                        u16* __restrict__ Wt,
                                                        int R, int Cc) {
  __shared__ float t[32][33];
  int tx = threadIdx.x, ty = threadIdx.y;
  int c0 = blockIdx.x * 32, r0 = blockIdx.y * 32;
#pragma unroll
  for (int i = 0; i < 4; ++i)
    t[ty + i * 8][tx] = W[(long)(r0 + ty + i * 8) * Cc + c0 + tx];
  __syncthreads();
#pragma unroll
  for (int i = 0; i < 4; ++i)
    Wt[(long)(c0 + ty + i * 8) * R + r0 + tx] = f2bf(t[tx][ty + i * 8]);
}

// ---------- GEMM: C[M][N] = A[M][K](bf16) * Bt[N][K](bf16)^T  (m97-style) ----------
// MODE 0: output bf16, no bias.  MODE 1: output fp32 + bias.
template <int MODE>
__global__ __launch_bounds__(256) void k_gemm_bt(const u16* __restrict__ A,
                                                 const u16* __restrict__ Bt,
                                                 void* __restrict__ Cout,
                                                 const float* __restrict__ bias,
                                                 int M, int N, int K) {
  __shared__ u16 a_t[128 * 64];
  __shared__ u16 b_t[128 * 64];
  int tid = threadIdx.x;
  int w = tid >> 6, l = tid & 63;
  int l15 = l & 15, lhi = l >> 4;
  int wm = w >> 1, wn = w & 1;
  int rowA = l >> 3, colA = (l & 7) * 8;
  const u16* Ab = A + (long)blockIdx.y * 128 * K;
  const u16* Bb = Bt + (long)blockIdx.x * 128 * K;
  f32x4 acc[4][4];
#pragma unroll
  for (int m = 0; m < 4; ++m)
#pragma unroll
    for (int n = 0; n < 4; ++n)
      acc[m][n] = (f32x4){0.f, 0.f, 0.f, 0.f};

  for (int k0 = 0; k0 < K; k0 += 64) {
#pragma unroll
    for (int i = 0; i < 4; ++i) {
      int ci = i * 4 + w;
      gload16(Ab + (long)(ci * 8 + rowA) * K + k0 + colA, &a_t[ci * 8 * 64]);
      gload16(Bb + (long)(ci * 8 + rowA) * K + k0 + colA, &b_t[ci * 8 * 64]);
    }
    __syncthreads();
#pragma unroll
    for (int kk = 0; kk < 2; ++kk) {
      s16x8 af[4], bfr[4];
#pragma unroll
      for (int m = 0; m < 4; ++m)
        af[m] = *(const s16x8*)&a_t[(wm * 64 + m * 16 + l15) * 64 + kk * 32 + lhi * 8];
#pragma unroll
      for (int n = 0; n < 4; ++n)
        bfr[n] = *(const s16x8*)&b_t[(wn * 64 + n * 16 + l15) * 64 + kk * 32 + lhi * 8];
#pragma unroll
      for (int m = 0; m < 4; ++m)
#pragma unroll
        for (int n = 0; n < 4; ++n)
          acc[m][n] = __builtin_amdgcn_mfma_f32_16x16x32_bf16(af[m], bfr[n], acc[m][n], 0, 0, 0);
    }
    __syncthreads();
  }
#pragma unroll
  for (int m = 0; m < 4; ++m) {
#pragma unroll
    for (int n = 0; n < 4; ++n) {
      int col = blockIdx.x * 128 + wn * 64 + n * 16 + l15;
#pragma unroll
      for (int r = 0; r < 4; ++r) {
        int row = blockIdx.y * 128 + wm * 64 + m * 16 + lhi * 4 + r;
        float v = acc[m][n][r];
        if (MODE == 1)
          ((float*)Cout)[(long)row * N + col] = v + bias[col];
        else
          ((u16*)Cout)[(long)row * N + col] = f2bf(v);
      }
    }
  }
}

// ---------- LayerNorm(Dh=64) on q,k + split/transpose to [B*H][N][64] ----------
// Folds the attention softmax scale (1/8) into the Q LayerNorm output.
__global__ __launch_bounds__(256) void k_ln_split(const u16* __restrict__ qkvb,
                                                  const float* __restrict__ qg,
                                                  const float* __restrict__ qbeta,
                                                  const float* __restrict__ kg,
                                                  const float* __restrict__ kbeta,
                                                  u16* __restrict__ Qh,
                                                  u16* __restrict__ Kh,
                                                  u16* __restrict__ Vh) {
  int wid = threadIdx.x >> 6, l = threadIdx.x & 63;
  const long nrows = (long)BN_ * 3 * H_;  // 196608 rows of 64
  for (long row = (long)blockIdx.x * 4 + wid; row < nrows; row += (long)gridDim.x * 4) {
    float v = bf2f(qkvb[row * 64 + l]);
    int h = (int)(row & 15);
    long t1 = row >> 4;           // (b*N+n)*3 + s
    int s = (int)(t1 % 3);
    long bn = t1 / 3;             // b*N + n
    long orow = ((bn >> 11) * H_ + h) * (long)N_ + (bn & (N_ - 1));
    if (s == 2) {
      Vh[orow * 64 + l] = f2bf(v);
      continue;
    }
    float m = v;
#pragma unroll
    for (int o = 1; o < 64; o <<= 1) m += __shfl_xor(m, o);
    m *= (1.f / 64.f);
    float d = v - m;
    float va = d * d;
#pragma unroll
    for (int o = 1; o < 64; o <<= 1) va += __shfl_xor(va, o);
    va *= (1.f / 64.f);
    float rs = rsqrtf(va + 1e-6f);
    float y = (s == 0) ? 0.125f * (qg[l] * d * rs + qbeta[l])
                       : (kg[l] * d * rs + kbeta[l]);
    u16* O = (s == 0) ? Qh : Kh;
    O[orow * 64 + l] = f2bf(y);
  }
}

// ---------- V [bh][N][64] -> Vt [bh][64][N] (bf16 transpose) ----------
__global__ __launch_bounds__(512) void k_transpose_v(const u16* __restrict__ Vh,
                                                     u16* __restrict__ Vt) {
  __shared__ u16 t[64][65];
  int tx = threadIdx.x, ty = threadIdx.y;  // (64,8)
  int bh = blockIdx.y;
  int n0 = blockIdx.x * 64;
#pragma unroll
  for (int i = 0; i < 8; ++i)
    t[ty + i * 8][tx] = Vh[((long)bh * N_ + n0 + ty + i * 8) * 64 + tx];
  __syncthreads();
#pragma unroll
  for (int i = 0; i < 8; ++i)
    Vt[((long)bh * 64 + ty + i * 8) * N_ + n0 + tx] = t[tx][ty + i * 8];
}

// ---------- flash attention ----------
// QBLK=64 (16 q-rows/wave), KVBLK=64, double-buffered swizzled K/V LDS,
// async stage of tile t+1 issued between QK^T(t) and softmax(t).
// All LDS buffers [64 rows][64 cols] bf16; 16B slot c of row r at phys
// slot c ^ (r&7). Since every fragment read has row&7 == l15&7, the XOR
// term is per-lane loop-invariant -> 2 address bases, rest immediates.
__global__ __launch_bounds__(256, 4) void k_attn(const u16* __restrict__ Qh,
                                                 const u16* __restrict__ Kh,
                                                 const u16* __restrict__ Vt,
                                                 u16* __restrict__ O) {
  __shared__ u16 k_t[2][64 * 64];
  __shared__ u16 v_t[2][64 * 64];
  __shared__ u16 p_t[64 * 64];
  int tid = threadIdx.x;
  int w = tid >> 6, l = tid & 63;
  int l15 = l & 15, lhi = l >> 4;
  int qb = blockIdx.x, bh = blockIdx.y;
  int b = bh >> 4, h = bh & 15;
  const u16* Qb = Qh + ((long)bh * N_ + qb * 64) * 64;
  const u16* Kb = Kh + (long)bh * N_ * 64;
  const u16* Vb = Vt + (long)bh * 64 * N_;

  // Q fragments: wave w owns q-rows w*16 .. w*16+15 (Q pre-scaled by 1/8 in LN)
  s16x8 qf[2];
#pragma unroll
  for (int kk = 0; kk < 2; ++kk)
    qf[kk] = *(const s16x8*)&Qb[(w * 16 + l15) * 64 + kk * 32 + lhi * 8];

  f32x4 acc[4];
#pragma unroll
  for (int nd = 0; nd < 4; ++nd) acc[nd] = (f32x4){0.f, 0.f, 0.f, 0.f};
  float mrow[4], lrow[4];
#pragma unroll
  for (int r = 0; r < 4; ++r) { mrow[r] = -3e38f; lrow[r] = 0.f; }

  // staging lane geometry: 8-row stripes, swizzled source column
  int srow = l >> 3;
  int scol = ((l & 7) ^ srow) * 8;
  // loop-invariant swizzled fragment bases (elements)
  int x0 = (lhi ^ (l15 & 7)) * 8;
  int x1 = ((4 + lhi) ^ (l15 & 7)) * 8;
  int rb = l15 * 64;              // k_t / v_t fragment row base
  int pb = (w * 16 + l15) * 64;   // p_t fragment row base

  // prologue: stage tile 0 into buffer 0
#pragma unroll
  for (int i = 0; i < 2; ++i) {
    int ci = i * 4 + w;
    gload16(Kb + (long)(ci * 8 + srow) * 64 + scol, &k_t[0][ci * 512]);
    gload16(Vb + (long)(ci * 8 + srow) * N_ + scol, &v_t[0][ci * 512]);
  }
  __syncthreads();

  int cur = 0;
  for (int t = 0; t < N_ / 64; ++t) {
    // ---- S = Q K^T ----
    f32x4 s[4];
#pragma unroll
    for (int nf = 0; nf < 4; ++nf) s[nf] = (f32x4){0.f, 0.f, 0.f, 0.f};
#pragma unroll
    for (int nf = 0; nf < 4; ++nf) {
      s16x8 kf0 = *(const s16x8*)&k_t[cur][rb + x0 + nf * 1024];
      s[nf] = __builtin_amdgcn_mfma_f32_16x16x32_bf16(qf[0], kf0, s[nf], 0, 0, 0);
      s16x8 kf1 = *(const s16x8*)&k_t[cur][rb + x1 + nf * 1024];
      s[nf] = __builtin_amdgcn_mfma_f32_16x16x32_bf16(qf[1], kf1, s[nf], 0, 0, 0);
    }

    // ---- issue async stage of tile t+1 (hides HBM under softmax+PV) ----
    if (t < N_ / 64 - 1) {
      int kt2 = (t + 1) * 64;
      int nb = cur ^ 1;
#pragma unroll
      for (int i = 0; i < 2; ++i) {
        int ci = i * 4 + w;
        gload16(Kb + (long)(kt2 + ci * 8 + srow) * 64 + scol, &k_t[nb][ci * 512]);
        gload16(Vb + (long)(ci * 8 + srow) * N_ + kt2 + scol, &v_t[nb][ci * 512]);
      }
    }

    // ---- online softmax (row = lhi*4+r, col = nf*16+l15) ----
#pragma unroll
    for (int r = 0; r < 4; ++r) {
      float mx = fmaxf(fmaxf(s[0][r], s[1][r]), fmaxf(s[2][r], s[3][r]));
#pragma unroll
      for (int o = 1; o < 16; o <<= 1) mx = fmaxf(mx, __shfl_xor(mx, o));
      float mnew = fmaxf(mrow[r], mx);
      float alpha = __expf(mrow[r] - mnew);
      mrow[r] = mnew;
      float rsum = 0.f;
#pragma unroll
      for (int nf = 0; nf < 4; ++nf) {
        float p = __expf(s[nf][r] - mnew);
        s[nf][r] = p;
        rsum += p;
      }
#pragma unroll
      for (int o = 1; o < 16; o <<= 1) rsum += __shfl_xor(rsum, o);
      lrow[r] = lrow[r] * alpha + rsum;
#pragma unroll
      for (int nd = 0; nd < 4; ++nd) acc[nd][r] *= alpha;
    }

    // ---- P -> LDS (swizzled) ----
#pragma unroll
    for (int r = 0; r < 4; ++r) {
      int prow = w * 16 + lhi * 4 + r;
      int rx = (lhi * 4 + r) & 7;
#pragma unroll
      for (int nf = 0; nf < 4; ++nf) {
        int cph = (nf * 2 + (l15 >> 3)) ^ rx;
        p_t[prow * 64 + cph * 8 + (l15 & 7)] = f2bf(s[nf][r]);
      }
    }
    __syncthreads();  // P visible to all lanes

    // ---- O += P V ----
    s16x8 pa0 = *(const s16x8*)&p_t[pb + x0];
    s16x8 pa1 = *(const s16x8*)&p_t[pb + x1];
#pragma unroll
    for (int nd = 0; nd < 4; ++nd) {
      s16x8 vf0 = *(const s16x8*)&v_t[cur][rb + x0 + nd * 1024];
      acc[nd] = __builtin_amdgcn_mfma_f32_16x16x32_bf16(pa0, vf0, acc[nd], 0, 0, 0);
      s16x8 vf1 = *(const s16x8*)&v_t[cur][rb + x1 + nd * 1024];
      acc[nd] = __builtin_amdgcn_mfma_f32_16x16x32_bf16(pa1, vf1, acc[nd], 0, 0, 0);
    }
    __syncthreads();  // PV done (p_t reusable) + staged loads drained (vmcnt0 at barrier)
    cur ^= 1;
  }

  // ---- epilogue: O[b][q][h*64+d] = acc / l ----
#pragma unroll
  for (int r = 0; r < 4; ++r) {
    float inv = 1.f / lrow[r];
    int q = qb * 64 + w * 16 + lhi * 4 + r;
#pragma unroll
    for (int nd = 0; nd < 4; ++nd) {
      int d = nd * 16 + l15;
      O[((long)(b * N_ + q) * H_ + h) * 64 + d] = f2bf(acc[nd][r] * inv);
    }
  }
}

// ---------- launch ----------
extern "C" void kernel_launch(void* const* d_in, const int* in_sizes, int n_in,
                              void* d_out, int out_size, void* d_ws, size_t ws_size,
                              hipStream_t stream) {
  const float* x      = (const float*)d_in[0];
  const float* qkv_w  = (const float*)d_in[1];
  const float* q_g    = (const float*)d_in[2];
  const float* q_b    = (const float*)d_in[3];
  const float* k_g    = (const float*)d_in[4];
  const float* k_b    = (const float*)d_in[5];
  const float* proj_w = (const float*)d_in[6];
  const float* proj_b = (const float*)d_in[7];
  float* out = (float*)d_out;

  char* ws = (char*)d_ws;
  // byte offsets (all 256-aligned)
  u16* xb     = (u16*)(ws + 0);                       //  8 MB  [4096][1024]
  u16* wqkvT  = (u16*)(ws + 8388608);                 //  6 MB  [3072][1024]
  u16* wprojT = (u16*)(ws + 14680064);                //  2 MB  [1024][1024]
  u16* qkvb   = (u16*)(ws + 16777216);                // 24 MB  [4096][3072]
  u16* Qh     = (u16*)(ws + 41943040);                //  8 MB  [32][2048][64]
  u16* Kh     = (u16*)(ws + 50331648);                //  8 MB
  u16* Vh     = (u16*)(ws + 58720256);                //  8 MB
  u16* Vt     = (u16*)(ws + 67108864);                //  8 MB  [32][64][2048]
  u16* attnO  = xb;                                   // reuse (xb dead after QKV GEMM)

  k_cast_bf16<<<4096, 256, 0, stream>>>(x, xb, (BN_ * C_) / 4);
  k_transpose_cast<<<dim3(96, 32), dim3(32, 8), 0, stream>>>(qkv_w, wqkvT, C_, 3 * C_);
  k_transpose_cast<<<dim3(32, 32), dim3(32, 8), 0, stream>>>(proj_w, wprojT, C_, C_);
  k_gemm_bt<0><<<dim3(24, 32), 256, 0, stream>>>(xb, wqkvT, qkvb, nullptr, BN_, 3 * C_, C_);
  k_ln_split<<<2048, 256, 0, stream>>>(qkvb, q_g, q_b, k_g, k_b, Qh, Kh, Vh);
  k_transpose_v<<<dim3(32, 32), dim3(64, 8), 0, stream>>>(Vh, Vt);
  k_attn<<<dim3(32, 32), 256, 0, stream>>>(Qh, Kh, Vt, attnO);
  k_gemm_bt<1><<<dim3(8, 32), 256, 0, stream>>>(attnO, wprojT, out, proj_b, BN_, C_, C_);
}

// Round 5
// 188.967 us; speedup vs baseline: 1.4979x; 1.1969x over previous
//
#include <hip/hip_runtime.h>

typedef unsigned short u16;
typedef unsigned int u32;
typedef float f32x4 __attribute__((ext_vector_type(4)));
typedef float f32x16 __attribute__((ext_vector_type(16)));
typedef short s16x8 __attribute__((ext_vector_type(8)));

#define B_ 2
#define N_ 2048
#define C_ 1024
#define H_ 16
#define BN_ (B_*N_)   // 4096 rows

// ---------- helpers ----------
__device__ __forceinline__ u16 f2bf(float f) {
  union { float f; unsigned u; } c; c.f = f;
  unsigned u = c.u;
  u = (u + 0x7fffu + ((u >> 16) & 1u)) >> 16;   // RNE
  return (u16)u;
}
__device__ __forceinline__ float bf2f(u16 h) {
  union { unsigned u; float f; } c; c.u = ((unsigned)h) << 16;
  return c.f;
}
__device__ __forceinline__ u32 pack2(float lo, float hi) {
  return (u32)f2bf(lo) | ((u32)f2bf(hi) << 16);
}
__device__ __forceinline__ void gload16(const u16* g, u16* l) {
  __builtin_amdgcn_global_load_lds(
      (const __attribute__((address_space(1))) unsigned*)g,
      (__attribute__((address_space(3))) unsigned*)l, 16, 0, 0);
}

// ---------- fp32 -> bf16 cast (vectorized) ----------
__global__ __launch_bounds__(256) void k_cast_bf16(const float* __restrict__ x,
                                                   u16* __restrict__ o, int n4) {
  int i = blockIdx.x * blockDim.x + threadIdx.x;
  if (i >= n4) return;
  float4 v = ((const float4*)x)[i];
  ushort4 r;
  r.x = f2bf(v.x); r.y = f2bf(v.y); r.z = f2bf(v.z); r.w = f2bf(v.w);
  ((ushort4*)o)[i] = r;
}

// ---------- fp32 [R][C] -> bf16 [C][R] transpose+cast ----------
__global__ __launch_bounds__(256) void k_transpose_cast(const float* __restrict__ W,
                                                        u16* __restrict__ Wt,
                                                        int R, int Cc) {
  __shared__ float t[32][33];
  int tx = threadIdx.x, ty = threadIdx.y;
  int c0 = blockIdx.x * 32, r0 = blockIdx.y * 32;
#pragma unroll
  for (int i = 0; i < 4; ++i)
    t[ty + i * 8][tx] = W[(long)(r0 + ty + i * 8) * Cc + c0 + tx];
  __syncthreads();
#pragma unroll
  for (int i = 0; i < 4; ++i)
    Wt[(long)(c0 + ty + i * 8) * R + r0 + tx] = f2bf(t[tx][ty + i * 8]);
}

// ---------- GEMM: C[M][N] = A[M][K](bf16) * Bt[N][K](bf16)^T  (m97-style) ----------
// MODE 0: output bf16, no bias.  MODE 1: output fp32 + bias.
template <int MODE>
__global__ __launch_bounds__(256) void k_gemm_bt(const u16* __restrict__ A,
                                                 const u16* __restrict__ Bt,
                                                 void* __restrict__ Cout,
                                                 const float* __restrict__ bias,
                                                 int M, int N, int K) {
  __shared__ u16 a_t[128 * 64];
  __shared__ u16 b_t[128 * 64];
  int tid = threadIdx.x;
  int w = tid >> 6, l = tid & 63;
  int l15 = l & 15, lhi = l >> 4;
  int wm = w >> 1, wn = w & 1;
  int rowA = l >> 3, colA = (l & 7) * 8;
  const u16* Ab = A + (long)blockIdx.y * 128 * K;
  const u16* Bb = Bt + (long)blockIdx.x * 128 * K;
  f32x4 acc[4][4];
#pragma unroll
  for (int m = 0; m < 4; ++m)
#pragma unroll
    for (int n = 0; n < 4; ++n)
      acc[m][n] = (f32x4){0.f, 0.f, 0.f, 0.f};

  for (int k0 = 0; k0 < K; k0 += 64) {
#pragma unroll
    for (int i = 0; i < 4; ++i) {
      int ci = i * 4 + w;
      gload16(Ab + (long)(ci * 8 + rowA) * K + k0 + colA, &a_t[ci * 8 * 64]);
      gload16(Bb + (long)(ci * 8 + rowA) * K + k0 + colA, &b_t[ci * 8 * 64]);
    }
    __syncthreads();
#pragma unroll
    for (int kk = 0; kk < 2; ++kk) {
      s16x8 af[4], bfr[4];
#pragma unroll
      for (int m = 0; m < 4; ++m)
        af[m] = *(const s16x8*)&a_t[(wm * 64 + m * 16 + l15) * 64 + kk * 32 + lhi * 8];
#pragma unroll
      for (int n = 0; n < 4; ++n)
        bfr[n] = *(const s16x8*)&b_t[(wn * 64 + n * 16 + l15) * 64 + kk * 32 + lhi * 8];
#pragma unroll
      for (int m = 0; m < 4; ++m)
#pragma unroll
        for (int n = 0; n < 4; ++n)
          acc[m][n] = __builtin_amdgcn_mfma_f32_16x16x32_bf16(af[m], bfr[n], acc[m][n], 0, 0, 0);
    }
    __syncthreads();
  }
#pragma unroll
  for (int m = 0; m < 4; ++m) {
#pragma unroll
    for (int n = 0; n < 4; ++n) {
      int col = blockIdx.x * 128 + wn * 64 + n * 16 + l15;
#pragma unroll
      for (int r = 0; r < 4; ++r) {
        int row = blockIdx.y * 128 + wm * 64 + m * 16 + lhi * 4 + r;
        float v = acc[m][n][r];
        if (MODE == 1)
          ((float*)Cout)[(long)row * N + col] = v + bias[col];
        else
          ((u16*)Cout)[(long)row * N + col] = f2bf(v);
      }
    }
  }
}

// ---------- LayerNorm(Dh=64) on q,k + split/transpose to [B*H][N][64] ----------
// Folds the attention softmax scale (1/8) into the Q LayerNorm output.
__global__ __launch_bounds__(256) void k_ln_split(const u16* __restrict__ qkvb,
                                                  const float* __restrict__ qg,
                                                  const float* __restrict__ qbeta,
                                                  const float* __restrict__ kg,
                                                  const float* __restrict__ kbeta,
                                                  u16* __restrict__ Qh,
                                                  u16* __restrict__ Kh,
                                                  u16* __restrict__ Vh) {
  int wid = threadIdx.x >> 6, l = threadIdx.x & 63;
  const long nrows = (long)BN_ * 3 * H_;  // 196608 rows of 64
  for (long row = (long)blockIdx.x * 4 + wid; row < nrows; row += (long)gridDim.x * 4) {
    float v = bf2f(qkvb[row * 64 + l]);
    int h = (int)(row & 15);
    long t1 = row >> 4;           // (b*N+n)*3 + s
    int s = (int)(t1 % 3);
    long bn = t1 / 3;             // b*N + n
    long orow = ((bn >> 11) * H_ + h) * (long)N_ + (bn & (N_ - 1));
    if (s == 2) {
      Vh[orow * 64 + l] = f2bf(v);
      continue;
    }
    float m = v;
#pragma unroll
    for (int o = 1; o < 64; o <<= 1) m += __shfl_xor(m, o);
    m *= (1.f / 64.f);
    float d = v - m;
    float va = d * d;
#pragma unroll
    for (int o = 1; o < 64; o <<= 1) va += __shfl_xor(va, o);
    va *= (1.f / 64.f);
    float rs = rsqrtf(va + 1e-6f);
    float y = (s == 0) ? 0.125f * (qg[l] * d * rs + qbeta[l])
                       : (kg[l] * d * rs + kbeta[l]);
    u16* O = (s == 0) ? Qh : Kh;
    O[orow * 64 + l] = f2bf(y);
  }
}

// ---------- V [bh][N][64] -> Vt [bh][64][N] (bf16 transpose) ----------
__global__ __launch_bounds__(512) void k_transpose_v(const u16* __restrict__ Vh,
                                                     u16* __restrict__ Vt) {
  __shared__ u16 t[64][65];
  int tx = threadIdx.x, ty = threadIdx.y;  // (64,8)
  int bh = blockIdx.y;
  int n0 = blockIdx.x * 64;
#pragma unroll
  for (int i = 0; i < 8; ++i)
    t[ty + i * 8][tx] = Vh[((long)bh * N_ + n0 + ty + i * 8) * 64 + tx];
  __syncthreads();
#pragma unroll
  for (int i = 0; i < 8; ++i)
    Vt[((long)bh * 64 + ty + i * 8) * N_ + n0 + tx] = t[tx][ty + i * 8];
}

// ---------- flash attention: swapped-QK^T 32x32 + in-register softmax ----------
// Qh (pre-scaled 1/8), Kh: [bh][N][64]; Vt: [bh][64 d][N k]; O: [B][N][H*64].
// Per wave: 32 q-rows (q = lane&31). S^T = mfma_32x32x16(A=K, B=Q) so each
// lane holds P[q=l31][key=crow(r,hi)], crow=(r&3)+8*(r>>2)+4*hi (+32 for s1).
// Softmax lane-local + one cross-half exchange (__shfl_xor 32). P -> PV
// A-fragments via explicit f2bf packing + 2 shfl_xor(32) per 16-key group
// (boring primitives only; no cvt_pk / permlane asm). T13 defer-max (THR=8;
// with random data triggers only at t=0 where acc=lsum=0). K/V double-
// buffered in swizzled LDS (phys 16B slot = c ^ (row&7)), staged with
// global_load_lds from pre-swizzled global addresses.
__global__ __launch_bounds__(256, 2) void k_attn(const u16* __restrict__ Qh,
                                                 const u16* __restrict__ Kh,
                                                 const u16* __restrict__ Vt,
                                                 u16* __restrict__ O) {
  __shared__ u16 k_t[2][64 * 64];
  __shared__ u16 v_t[2][64 * 64];
  int tid = threadIdx.x;
  int w = tid >> 6, l = tid & 63;
  int l31 = l & 31, hi = l >> 5;
  int qb = blockIdx.x, bh = blockIdx.y;
  int b = bh >> 4, h = bh & 15;
  const u16* Qb = Qh + ((long)bh * N_ + qb * 128 + w * 32) * 64;
  const u16* Kb = Kh + (long)bh * N_ * 64;
  const u16* Vb = Vt + (long)bh * 64 * N_;

  // Q as B-operand fragments: B[k=d][col=q=lane&31], d = j*16 + hi*8 + e
  s16x8 qf[4];
#pragma unroll
  for (int j = 0; j < 4; ++j)
    qf[j] = *(const s16x8*)&Qb[l31 * 64 + j * 16 + hi * 8];

  f32x16 acc0, acc1;
#pragma unroll
  for (int i = 0; i < 16; ++i) { acc0[i] = 0.f; acc1[i] = 0.f; }
  float m = -3e38f, lsum = 0.f;

  // fragment read offsets: row (t*32+l31), 16B slot (j*2+hi)^(l&7)
  int off[2][4];
#pragma unroll
  for (int t = 0; t < 2; ++t)
#pragma unroll
    for (int j = 0; j < 4; ++j)
      off[t][j] = (t * 32 + l31) * 64 + (((j * 2 + hi) ^ (l & 7)) * 8);

  // staging geometry (8-row stripes, pre-swizzled source column)
  int srow = l >> 3;
  int scol = ((l & 7) ^ srow) * 8;

  // prologue: stage tile 0 into buffer 0
#pragma unroll
  for (int i = 0; i < 2; ++i) {
    int ci = i * 4 + w;
    gload16(Kb + (long)(ci * 8 + srow) * 64 + scol, &k_t[0][ci * 512]);
    gload16(Vb + (long)(ci * 8 + srow) * N_ + scol, &v_t[0][ci * 512]);
  }
  __syncthreads();

  int cur = 0;
  for (int t = 0; t < N_ / 64; ++t) {
    // issue async stage of tile t+1 (drained by the end-of-iter barrier)
    if (t < N_ / 64 - 1) {
      int kt2 = (t + 1) * 64;
      int nb = cur ^ 1;
#pragma unroll
      for (int i = 0; i < 2; ++i) {
        int ci = i * 4 + w;
        gload16(Kb + (long)(kt2 + ci * 8 + srow) * 64 + scol, &k_t[nb][ci * 512]);
        gload16(Vb + (long)(ci * 8 + srow) * N_ + kt2 + scol, &v_t[nb][ci * 512]);
      }
    }
    const u16* kb = k_t[cur];
    const u16* vb = v_t[cur];

    // ---- S^T = mfma(K, Q): lane q=l31; s0 = keys 0..31, s1 = keys 32..63 ----
    f32x16 s0, s1;
#pragma unroll
    for (int i = 0; i < 16; ++i) { s0[i] = 0.f; s1[i] = 0.f; }
#pragma unroll
    for (int j = 0; j < 4; ++j) {
      s16x8 kf0 = *(const s16x8*)&kb[off[0][j]];
      s0 = __builtin_amdgcn_mfma_f32_32x32x16_bf16(kf0, qf[j], s0, 0, 0, 0);
      s16x8 kf1 = *(const s16x8*)&kb[off[1][j]];
      s1 = __builtin_amdgcn_mfma_f32_32x32x16_bf16(kf1, qf[j], s1, 0, 0, 0);
    }

    // ---- row max: in-lane tree + one cross-half exchange ----
    f32x16 mx;
#pragma unroll
    for (int i = 0; i < 16; ++i) mx[i] = fmaxf(s0[i], s1[i]);
#pragma unroll
    for (int i = 0; i < 8; ++i) mx[i] = fmaxf(mx[i], mx[i + 8]);
#pragma unroll
    for (int i = 0; i < 4; ++i) mx[i] = fmaxf(mx[i], mx[i + 4]);
    float pm = fmaxf(fmaxf(mx[0], mx[1]), fmaxf(mx[2], mx[3]));
    pm = fmaxf(pm, __shfl_xor(pm, 32));

    // ---- defer-max rescale (rare; wave-uniform branch) ----
    if (__ballot(pm > m + 8.0f)) {
      float mnew = fmaxf(m, pm);
      float alpha = __expf(m - mnew);
      m = mnew;
      lsum *= alpha;
      int ai = __float_as_int(alpha);
#pragma unroll
      for (int r = 0; r < 16; ++r) {
        int ql = (r & 3) + 8 * (r >> 2) + 4 * hi;
        float ar = __int_as_float(__builtin_amdgcn_ds_bpermute(ql << 2, ai));
        acc0[r] *= ar;
        acc1[r] *= ar;
      }
    }

    // ---- P = exp(S - m), row sum ----
#pragma unroll
    for (int i = 0; i < 16; ++i) {
      s0[i] = __expf(s0[i] - m);
      s1[i] = __expf(s1[i] - m);
    }
    f32x16 sm;
#pragma unroll
    for (int i = 0; i < 16; ++i) sm[i] = s0[i] + s1[i];
#pragma unroll
    for (int i = 0; i < 8; ++i) sm[i] += sm[i + 8];
#pragma unroll
    for (int i = 0; i < 4; ++i) sm[i] += sm[i + 4];
    float rs = (sm[0] + sm[1]) + (sm[2] + sm[3]);
    lsum += rs + __shfl_xor(rs, 32);

    // ---- pack P into PV A-fragments ----
    // group g (16 keys): own words w01=(4hi+0,1) w23=(4hi+2,3)
    //                    w45=(8+4hi,9+4hi) w67=(10+4hi,11+4hi)
    // send = hi ? w01/w23 : w45/w67; recv = partner's counterpart.
    // hi=0 frag words: [w01, w23, recvA, recvB]; hi=1: [recvA, recvB, w45, w67]
    s16x8 pa[4];
#pragma unroll
    for (int g = 0; g < 4; ++g) {
      const f32x16& sv = (g < 2) ? s0 : s1;
      int o = (g & 1) * 8;
      u32 w01 = pack2(sv[o + 0], sv[o + 1]);
      u32 w23 = pack2(sv[o + 2], sv[o + 3]);
      u32 w45 = pack2(sv[o + 4], sv[o + 5]);
      u32 w67 = pack2(sv[o + 6], sv[o + 7]);
      u32 recvA = __shfl_xor(hi ? w01 : w45, 32);
      u32 recvB = __shfl_xor(hi ? w23 : w67, 32);
      union { u32 u[4]; s16x8 v; } fr;
      fr.u[0] = hi ? recvA : w01;
      fr.u[1] = hi ? recvB : w23;
      fr.u[2] = hi ? w45 : recvA;
      fr.u[3] = hi ? w67 : recvB;
      pa[g] = fr.v;
    }

    // ---- O += P V : acc0 = d 0..31, acc1 = d 32..63 ----
#pragma unroll
    for (int j = 0; j < 4; ++j) {
      s16x8 vf0 = *(const s16x8*)&vb[off[0][j]];
      acc0 = __builtin_amdgcn_mfma_f32_32x32x16_bf16(pa[j], vf0, acc0, 0, 0, 0);
      s16x8 vf1 = *(const s16x8*)&vb[off[1][j]];
      acc1 = __builtin_amdgcn_mfma_f32_32x32x16_bf16(pa[j], vf1, acc1, 0, 0, 0);
    }
    __syncthreads();  // drains staged loads; releases cur for next stage
    cur ^= 1;
  }

  // ---- epilogue: O[b][q][h*64+d] = acc / lsum[q] ----
  int li = __float_as_int(lsum);
#pragma unroll
  for (int r = 0; r < 16; ++r) {
    int ql = (r & 3) + 8 * (r >> 2) + 4 * hi;
    float ls = __int_as_float(__builtin_amdgcn_ds_bpermute(ql << 2, li));
    float inv = 1.f / ls;
    int q = qb * 128 + w * 32 + ql;
    long ob = ((long)(b * N_ + q) * H_ + h) * 64 + l31;
    O[ob] = f2bf(acc0[r] * inv);
    O[ob + 32] = f2bf(acc1[r] * inv);
  }
}

// ---------- launch ----------
extern "C" void kernel_launch(void* const* d_in, const int* in_sizes, int n_in,
                              void* d_out, int out_size, void* d_ws, size_t ws_size,
                              hipStream_t stream) {
  const float* x      = (const float*)d_in[0];
  const float* qkv_w  = (const float*)d_in[1];
  const float* q_g    = (const float*)d_in[2];
  const float* q_b    = (const float*)d_in[3];
  const float* k_g    = (const float*)d_in[4];
  const float* k_b    = (const float*)d_in[5];
  const float* proj_w = (const float*)d_in[6];
  const float* proj_b = (const float*)d_in[7];
  float* out = (float*)d_out;

  char* ws = (char*)d_ws;
  // byte offsets (all 256-aligned)
  u16* xb     = (u16*)(ws + 0);                       //  8 MB  [4096][1024]
  u16* wqkvT  = (u16*)(ws + 8388608);                 //  6 MB  [3072][1024]
  u16* wprojT = (u16*)(ws + 14680064);                //  2 MB  [1024][1024]
  u16* qkvb   = (u16*)(ws + 16777216);                // 24 MB  [4096][3072]
  u16* Qh     = (u16*)(ws + 41943040);                //  8 MB  [32][2048][64]
  u16* Kh     = (u16*)(ws + 50331648);                //  8 MB
  u16* Vh     = (u16*)(ws + 58720256);                //  8 MB
  u16* Vt     = (u16*)(ws + 67108864);                //  8 MB  [32][64][2048]
  u16* attnO  = xb;                                   // reuse (xb dead after QKV GEMM)

  k_cast_bf16<<<4096, 256, 0, stream>>>(x, xb, (BN_ * C_) / 4);
  k_transpose_cast<<<dim3(96, 32), dim3(32, 8), 0, stream>>>(qkv_w, wqkvT, C_, 3 * C_);
  k_transpose_cast<<<dim3(32, 32), dim3(32, 8), 0, stream>>>(proj_w, wprojT, C_, C_);
  k_gemm_bt<0><<<dim3(24, 32), 256, 0, stream>>>(xb, wqkvT, qkvb, nullptr, BN_, 3 * C_, C_);
  k_ln_split<<<2048, 256, 0, stream>>>(qkvb, q_g, q_b, k_g, k_b, Qh, Kh, Vh);
  k_transpose_v<<<dim3(32, 32), dim3(64, 8), 0, stream>>>(Vh, Vt);
  k_attn<<<dim3(16, 32), 256, 0, stream>>>(Qh, Kh, Vt, attnO);
  k_gemm_bt<1><<<dim3(8, 32), 256, 0, stream>>>(attnO, wprojT, out, proj_b, BN_, C_, C_);
}

// Round 6
// 160.275 us; speedup vs baseline: 1.7661x; 1.1790x over previous
//
#include <hip/hip_runtime.h>

typedef unsigned short u16;
typedef unsigned int u32;
typedef float f32x4 __attribute__((ext_vector_type(4)));
typedef float f32x16 __attribute__((ext_vector_type(16)));
typedef short s16x8 __attribute__((ext_vector_type(8)));

#define B_ 2
#define N_ 2048
#define C_ 1024
#define H_ 16
#define BN_ (B_*N_)   // 4096 rows

// ---------- helpers ----------
__device__ __forceinline__ u16 f2bf(float f) {
  union { float f; unsigned u; } c; c.f = f;
  unsigned u = c.u;
  u = (u + 0x7fffu + ((u >> 16) & 1u)) >> 16;   // RNE
  return (u16)u;
}
__device__ __forceinline__ float bf2f(u16 h) {
  union { unsigned u; float f; } c; c.u = ((unsigned)h) << 16;
  return c.f;
}
// pack two f32 -> u32 of 2 bf16 via HW cvt (lo16 = src0, hi16 = src1; RNE)
__device__ __forceinline__ u32 pack2(float lo, float hi) {
  u32 r;
  asm("v_cvt_pk_bf16_f32 %0, %1, %2" : "=v"(r) : "v"(lo), "v"(hi));
  return r;
}
__device__ __forceinline__ void gload16(const u16* g, u16* l) {
  __builtin_amdgcn_global_load_lds(
      (const __attribute__((address_space(1))) unsigned*)g,
      (__attribute__((address_space(3))) unsigned*)l, 16, 0, 0);
}

// ---------- fp32 -> bf16 cast (vectorized) ----------
__global__ __launch_bounds__(256) void k_cast_bf16(const float* __restrict__ x,
                                                   u16* __restrict__ o, int n4) {
  int i = blockIdx.x * blockDim.x + threadIdx.x;
  if (i >= n4) return;
  float4 v = ((const float4*)x)[i];
  ushort4 r;
  r.x = f2bf(v.x); r.y = f2bf(v.y); r.z = f2bf(v.z); r.w = f2bf(v.w);
  ((ushort4*)o)[i] = r;
}

// ---------- fp32 [R][C] -> bf16 [C][R] transpose+cast ----------
__global__ __launch_bounds__(256) void k_transpose_cast(const float* __restrict__ W,
                                                        u16* __restrict__ Wt,
                                                        int R, int Cc) {
  __shared__ float t[32][33];
  int tx = threadIdx.x, ty = threadIdx.y;
  int c0 = blockIdx.x * 32, r0 = blockIdx.y * 32;
#pragma unroll
  for (int i = 0; i < 4; ++i)
    t[ty + i * 8][tx] = W[(long)(r0 + ty + i * 8) * Cc + c0 + tx];
  __syncthreads();
#pragma unroll
  for (int i = 0; i < 4; ++i)
    Wt[(long)(c0 + ty + i * 8) * R + r0 + tx] = f2bf(t[tx][ty + i * 8]);
}

// ---------- QKV GEMM with fused per-head LayerNorm epilogue ----------
// A: xb [4096][1024] bf16, Bt: wqkvT [3072][1024] bf16.
// Each warp's 64-col range = one head of one {q,k,v} section (128-col blocks
// are 1024-section-aligned). For fixed (m,r), the 64 head-values of a row sit
// in 4 in-lane regs (n) x 16 lanes (l15) at a fixed lhi, so LN mean/var =
// 3 in-lane adds + shfl_xor{1,2,4,8} (never crosses lhi; all 4 lhi rows
// reduce in parallel). Writes Qh (LN'd, x0.125), Kh (LN'd), Vh directly
// in [b*H+h][n][64] layout — no qkvb round-trip.
__global__ __launch_bounds__(256) void k_gemm_qkv_ln(const u16* __restrict__ A,
                                                     const u16* __restrict__ Bt,
                                                     const float* __restrict__ qg,
                                                     const float* __restrict__ qbeta,
                                                     const float* __restrict__ kg,
                                                     const float* __restrict__ kbeta,
                                                     u16* __restrict__ Qh,
                                                     u16* __restrict__ Kh,
                                                     u16* __restrict__ Vh) {
  const int K = C_;
  __shared__ u16 a_t[128 * 64];
  __shared__ u16 b_t[128 * 64];
  int tid = threadIdx.x;
  int w = tid >> 6, l = tid & 63;
  int l15 = l & 15, lhi = l >> 4;
  int wm = w >> 1, wn = w & 1;
  int rowA = l >> 3, colA = (l & 7) * 8;
  const u16* Ab = A + (long)blockIdx.y * 128 * K;
  const u16* Bb = Bt + (long)blockIdx.x * 128 * K;
  f32x4 acc[4][4];
#pragma unroll
  for (int m = 0; m < 4; ++m)
#pragma unroll
    for (int n = 0; n < 4; ++n)
      acc[m][n] = (f32x4){0.f, 0.f, 0.f, 0.f};

  for (int k0 = 0; k0 < K; k0 += 64) {
#pragma unroll
    for (int i = 0; i < 4; ++i) {
      int ci = i * 4 + w;
      gload16(Ab + (long)(ci * 8 + rowA) * K + k0 + colA, &a_t[ci * 8 * 64]);
      gload16(Bb + (long)(ci * 8 + rowA) * K + k0 + colA, &b_t[ci * 8 * 64]);
    }
    __syncthreads();
#pragma unroll
    for (int kk = 0; kk < 2; ++kk) {
      s16x8 af[4], bfr[4];
#pragma unroll
      for (int m = 0; m < 4; ++m)
        af[m] = *(const s16x8*)&a_t[(wm * 64 + m * 16 + l15) * 64 + kk * 32 + lhi * 8];
#pragma unroll
      for (int n = 0; n < 4; ++n)
        bfr[n] = *(const s16x8*)&b_t[(wn * 64 + n * 16 + l15) * 64 + kk * 32 + lhi * 8];
#pragma unroll
      for (int m = 0; m < 4; ++m)
#pragma unroll
        for (int n = 0; n < 4; ++n)
          acc[m][n] = __builtin_amdgcn_mfma_f32_16x16x32_bf16(af[m], bfr[n], acc[m][n], 0, 0, 0);
    }
    __syncthreads();
  }

  // ---- fused epilogue ----
  int cb = blockIdx.x * 128 + wn * 64;   // warp col base (64 cols = 1 head)
  int s = cb >> 10;                      // 0=q 1=k 2=v
  int h = (cb & 1023) >> 6;
  int rowbase = blockIdx.y * 128 + wm * 64;

  if (s == 2) {
#pragma unroll
    for (int m = 0; m < 4; ++m) {
#pragma unroll
      for (int r = 0; r < 4; ++r) {
        int row = rowbase + m * 16 + lhi * 4 + r;
        int b = row >> 11, nn = row & (N_ - 1);
        long ob = ((long)(b * H_ + h) * N_ + nn) * 64;
#pragma unroll
        for (int n = 0; n < 4; ++n)
          Vh[ob + n * 16 + l15] = f2bf(acc[m][n][r]);
      }
    }
  } else {
    const float* g = (s == 0) ? qg : kg;
    const float* be = (s == 0) ? qbeta : kbeta;
    u16* Oh = (s == 0) ? Qh : Kh;
    float sc = (s == 0) ? 0.125f : 1.f;
    float gv[4], bv[4];
#pragma unroll
    for (int n = 0; n < 4; ++n) { gv[n] = g[n * 16 + l15]; bv[n] = be[n * 16 + l15]; }
#pragma unroll
    for (int m = 0; m < 4; ++m) {
#pragma unroll
      for (int r = 0; r < 4; ++r) {
        float t = (acc[m][0][r] + acc[m][1][r]) + (acc[m][2][r] + acc[m][3][r]);
        t += __shfl_xor(t, 1); t += __shfl_xor(t, 2);
        t += __shfl_xor(t, 4); t += __shfl_xor(t, 8);
        float mean = t * (1.f / 64.f);
        float v0 = acc[m][0][r] - mean, v1 = acc[m][1][r] - mean;
        float v2 = acc[m][2][r] - mean, v3 = acc[m][3][r] - mean;
        float q2 = (v0 * v0 + v1 * v1) + (v2 * v2 + v3 * v3);
        q2 += __shfl_xor(q2, 1); q2 += __shfl_xor(q2, 2);
        q2 += __shfl_xor(q2, 4); q2 += __shfl_xor(q2, 8);
        float rs = rsqrtf(q2 * (1.f / 64.f) + 1e-6f);
        int row = rowbase + m * 16 + lhi * 4 + r;
        int b = row >> 11, nn = row & (N_ - 1);
        long ob = ((long)(b * H_ + h) * N_ + nn) * 64;
        float vv[4] = {v0, v1, v2, v3};
#pragma unroll
        for (int n = 0; n < 4; ++n)
          Oh[ob + n * 16 + l15] = f2bf(sc * (gv[n] * vv[n] * rs + bv[n]));
      }
    }
  }
}

// ---------- proj GEMM: C[M][N] = A*Bt^T, fp32 out + bias ----------
__global__ __launch_bounds__(256) void k_gemm_proj(const u16* __restrict__ A,
                                                   const u16* __restrict__ Bt,
                                                   float* __restrict__ Cout,
                                                   const float* __restrict__ bias,
                                                   int M, int N, int K) {
  __shared__ u16 a_t[128 * 64];
  __shared__ u16 b_t[128 * 64];
  int tid = threadIdx.x;
  int w = tid >> 6, l = tid & 63;
  int l15 = l & 15, lhi = l >> 4;
  int wm = w >> 1, wn = w & 1;
  int rowA = l >> 3, colA = (l & 7) * 8;
  const u16* Ab = A + (long)blockIdx.y * 128 * K;
  const u16* Bb = Bt + (long)blockIdx.x * 128 * K;
  f32x4 acc[4][4];
#pragma unroll
  for (int m = 0; m < 4; ++m)
#pragma unroll
    for (int n = 0; n < 4; ++n)
      acc[m][n] = (f32x4){0.f, 0.f, 0.f, 0.f};

  for (int k0 = 0; k0 < K; k0 += 64) {
#pragma unroll
    for (int i = 0; i < 4; ++i) {
      int ci = i * 4 + w;
      gload16(Ab + (long)(ci * 8 + rowA) * K + k0 + colA, &a_t[ci * 8 * 64]);
      gload16(Bb + (long)(ci * 8 + rowA) * K + k0 + colA, &b_t[ci * 8 * 64]);
    }
    __syncthreads();
#pragma unroll
    for (int kk = 0; kk < 2; ++kk) {
      s16x8 af[4], bfr[4];
#pragma unroll
      for (int m = 0; m < 4; ++m)
        af[m] = *(const s16x8*)&a_t[(wm * 64 + m * 16 + l15) * 64 + kk * 32 + lhi * 8];
#pragma unroll
      for (int n = 0; n < 4; ++n)
        bfr[n] = *(const s16x8*)&b_t[(wn * 64 + n * 16 + l15) * 64 + kk * 32 + lhi * 8];
#pragma unroll
      for (int m = 0; m < 4; ++m)
#pragma unroll
        for (int n = 0; n < 4; ++n)
          acc[m][n] = __builtin_amdgcn_mfma_f32_16x16x32_bf16(af[m], bfr[n], acc[m][n], 0, 0, 0);
    }
    __syncthreads();
  }
#pragma unroll
  for (int m = 0; m < 4; ++m) {
#pragma unroll
    for (int n = 0; n < 4; ++n) {
      int col = blockIdx.x * 128 + wn * 64 + n * 16 + l15;
#pragma unroll
      for (int r = 0; r < 4; ++r) {
        int row = blockIdx.y * 128 + wm * 64 + m * 16 + lhi * 4 + r;
        Cout[(long)row * N + col] = acc[m][n][r] + bias[col];
      }
    }
  }
}

// ---------- V [bh][N][64] -> Vt [bh][64][N] (bf16 transpose) ----------
__global__ __launch_bounds__(512) void k_transpose_v(const u16* __restrict__ Vh,
                                                     u16* __restrict__ Vt) {
  __shared__ u16 t[64][65];
  int tx = threadIdx.x, ty = threadIdx.y;  // (64,8)
  int bh = blockIdx.y;
  int n0 = blockIdx.x * 64;
#pragma unroll
  for (int i = 0; i < 8; ++i)
    t[ty + i * 8][tx] = Vh[((long)bh * N_ + n0 + ty + i * 8) * 64 + tx];
  __syncthreads();
#pragma unroll
  for (int i = 0; i < 8; ++i)
    Vt[((long)bh * 64 + ty + i * 8) * N_ + n0 + tx] = t[tx][ty + i * 8];
}

// ---------- flash attention: swapped-QK^T 32x32 + in-register softmax ----------
// Qh (pre-scaled 1/8), Kh: [bh][N][64]; Vt: [bh][64 d][N k]; O: [B][N][H*64].
// Per wave: 32 q-rows (q = lane&31). S^T = mfma_32x32x16(A=K, B=Q) so each
// lane holds P[q=l31][key=crow(r,hi)], crow=(r&3)+8*(r>>2)+4*hi (+32 for s1).
// Softmax lane-local + one cross-half exchange (__shfl_xor 32). P -> PV
// A-fragments via v_cvt_pk_bf16_f32 + 2 shfl_xor(32) per 16-key group.
// T13 defer-max (THR=8). K/V double-buffered in swizzled LDS (phys 16B slot
// = c ^ (row&7)), staged via global_load_lds from pre-swizzled global addrs.
__global__ __launch_bounds__(256, 2) void k_attn(const u16* __restrict__ Qh,
                                                 const u16* __restrict__ Kh,
                                                 const u16* __restrict__ Vt,
                                                 u16* __restrict__ O) {
  __shared__ u16 k_t[2][64 * 64];
  __shared__ u16 v_t[2][64 * 64];
  int tid = threadIdx.x;
  int w = tid >> 6, l = tid & 63;
  int l31 = l & 31, hi = l >> 5;
  int qb = blockIdx.x, bh = blockIdx.y;
  int b = bh >> 4, h = bh & 15;
  const u16* Qb = Qh + ((long)bh * N_ + qb * 128 + w * 32) * 64;
  const u16* Kb = Kh + (long)bh * N_ * 64;
  const u16* Vb = Vt + (long)bh * 64 * N_;

  // Q as B-operand fragments: B[k=d][col=q=lane&31], d = j*16 + hi*8 + e
  s16x8 qf[4];
#pragma unroll
  for (int j = 0; j < 4; ++j)
    qf[j] = *(const s16x8*)&Qb[l31 * 64 + j * 16 + hi * 8];

  f32x16 acc0, acc1;
#pragma unroll
  for (int i = 0; i < 16; ++i) { acc0[i] = 0.f; acc1[i] = 0.f; }
  float m = -3e38f, lsum = 0.f;

  // fragment read offsets: row (t*32+l31), 16B slot (j*2+hi)^(l&7)
  int off[2][4];
#pragma unroll
  for (int t = 0; t < 2; ++t)
#pragma unroll
    for (int j = 0; j < 4; ++j)
      off[t][j] = (t * 32 + l31) * 64 + (((j * 2 + hi) ^ (l & 7)) * 8);

  // staging geometry (8-row stripes, pre-swizzled source column)
  int srow = l >> 3;
  int scol = ((l & 7) ^ srow) * 8;

  // prologue: stage tile 0 into buffer 0
#pragma unroll
  for (int i = 0; i < 2; ++i) {
    int ci = i * 4 + w;
    gload16(Kb + (long)(ci * 8 + srow) * 64 + scol, &k_t[0][ci * 512]);
    gload16(Vb + (long)(ci * 8 + srow) * N_ + scol, &v_t[0][ci * 512]);
  }
  __syncthreads();

  int cur = 0;
  for (int t = 0; t < N_ / 64; ++t) {
    // issue async stage of tile t+1 (drained by the end-of-iter barrier)
    if (t < N_ / 64 - 1) {
      int kt2 = (t + 1) * 64;
      int nb = cur ^ 1;
#pragma unroll
      for (int i = 0; i < 2; ++i) {
        int ci = i * 4 + w;
        gload16(Kb + (long)(kt2 + ci * 8 + srow) * 64 + scol, &k_t[nb][ci * 512]);
        gload16(Vb + (long)(ci * 8 + srow) * N_ + kt2 + scol, &v_t[nb][ci * 512]);
      }
    }
    const u16* kb = k_t[cur];
    const u16* vb = v_t[cur];

    // ---- S^T = mfma(K, Q): lane q=l31; s0 = keys 0..31, s1 = keys 32..63 ----
    f32x16 s0, s1;
#pragma unroll
    for (int i = 0; i < 16; ++i) { s0[i] = 0.f; s1[i] = 0.f; }
#pragma unroll
    for (int j = 0; j < 4; ++j) {
      s16x8 kf0 = *(const s16x8*)&kb[off[0][j]];
      s0 = __builtin_amdgcn_mfma_f32_32x32x16_bf16(kf0, qf[j], s0, 0, 0, 0);
      s16x8 kf1 = *(const s16x8*)&kb[off[1][j]];
      s1 = __builtin_amdgcn_mfma_f32_32x32x16_bf16(kf1, qf[j], s1, 0, 0, 0);
    }

    // ---- row max: in-lane tree + one cross-half exchange ----
    f32x16 mx;
#pragma unroll
    for (int i = 0; i < 16; ++i) mx[i] = fmaxf(s0[i], s1[i]);
#pragma unroll
    for (int i = 0; i < 8; ++i) mx[i] = fmaxf(mx[i], mx[i + 8]);
#pragma unroll
    for (int i = 0; i < 4; ++i) mx[i] = fmaxf(mx[i], mx[i + 4]);
    float pm = fmaxf(fmaxf(mx[0], mx[1]), fmaxf(mx[2], mx[3]));
    pm = fmaxf(pm, __shfl_xor(pm, 32));

    // ---- defer-max rescale (rare; wave-uniform branch) ----
    if (__ballot(pm > m + 8.0f)) {
      float mnew = fmaxf(m, pm);
      float alpha = __expf(m - mnew);
      m = mnew;
      lsum *= alpha;
      int ai = __float_as_int(alpha);
#pragma unroll
      for (int r = 0; r < 16; ++r) {
        int ql = (r & 3) + 8 * (r >> 2) + 4 * hi;
        float ar = __int_as_float(__builtin_amdgcn_ds_bpermute(ql << 2, ai));
        acc0[r] *= ar;
        acc1[r] *= ar;
      }
    }

    // ---- P = exp(S - m), row sum ----
#pragma unroll
    for (int i = 0; i < 16; ++i) {
      s0[i] = __expf(s0[i] - m);
      s1[i] = __expf(s1[i] - m);
    }
    f32x16 sm;
#pragma unroll
    for (int i = 0; i < 16; ++i) sm[i] = s0[i] + s1[i];
#pragma unroll
    for (int i = 0; i < 8; ++i) sm[i] += sm[i + 8];
#pragma unroll
    for (int i = 0; i < 4; ++i) sm[i] += sm[i + 4];
    float rs = (sm[0] + sm[1]) + (sm[2] + sm[3]);
    lsum += rs + __shfl_xor(rs, 32);

    // ---- pack P into PV A-fragments ----
    // group g (16 keys): own words w01=(4hi+0,1) w23=(4hi+2,3)
    //                    w45=(8+4hi,9+4hi) w67=(10+4hi,11+4hi)
    // send = hi ? w01/w23 : w45/w67; recv = partner's counterpart.
    // hi=0 frag words: [w01, w23, recvA, recvB]; hi=1: [recvA, recvB, w45, w67]
    s16x8 pa[4];
#pragma unroll
    for (int g = 0; g < 4; ++g) {
      const f32x16& sv = (g < 2) ? s0 : s1;
      int o = (g & 1) * 8;
      u32 w01 = pack2(sv[o + 0], sv[o + 1]);
      u32 w23 = pack2(sv[o + 2], sv[o + 3]);
      u32 w45 = pack2(sv[o + 4], sv[o + 5]);
      u32 w67 = pack2(sv[o + 6], sv[o + 7]);
      u32 recvA = __shfl_xor(hi ? w01 : w45, 32);
      u32 recvB = __shfl_xor(hi ? w23 : w67, 32);
      union { u32 u[4]; s16x8 v; } fr;
      fr.u[0] = hi ? recvA : w01;
      fr.u[1] = hi ? recvB : w23;
      fr.u[2] = hi ? w45 : recvA;
      fr.u[3] = hi ? w67 : recvB;
      pa[g] = fr.v;
    }

    // ---- O += P V : acc0 = d 0..31, acc1 = d 32..63 ----
#pragma unroll
    for (int j = 0; j < 4; ++j) {
      s16x8 vf0 = *(const s16x8*)&vb[off[0][j]];
      acc0 = __builtin_amdgcn_mfma_f32_32x32x16_bf16(pa[j], vf0, acc0, 0, 0, 0);
      s16x8 vf1 = *(const s16x8*)&vb[off[1][j]];
      acc1 = __builtin_amdgcn_mfma_f32_32x32x16_bf16(pa[j], vf1, acc1, 0, 0, 0);
    }
    __syncthreads();  // drains staged loads; releases cur for next stage
    cur ^= 1;
  }

  // ---- epilogue: O[b][q][h*64+d] = acc / lsum[q] ----
  int li = __float_as_int(lsum);
#pragma unroll
  for (int r = 0; r < 16; ++r) {
    int ql = (r & 3) + 8 * (r >> 2) + 4 * hi;
    float ls = __int_as_float(__builtin_amdgcn_ds_bpermute(ql << 2, li));
    float inv = 1.f / ls;
    int q = qb * 128 + w * 32 + ql;
    long ob = ((long)(b * N_ + q) * H_ + h) * 64 + l31;
    O[ob] = f2bf(acc0[r] * inv);
    O[ob + 32] = f2bf(acc1[r] * inv);
  }
}

// ---------- launch ----------
extern "C" void kernel_launch(void* const* d_in, const int* in_sizes, int n_in,
                              void* d_out, int out_size, void* d_ws, size_t ws_size,
                              hipStream_t stream) {
  const float* x      = (const float*)d_in[0];
  const float* qkv_w  = (const float*)d_in[1];
  const float* q_g    = (const float*)d_in[2];
  const float* q_b    = (const float*)d_in[3];
  const float* k_g    = (const float*)d_in[4];
  const float* k_b    = (const float*)d_in[5];
  const float* proj_w = (const float*)d_in[6];
  const float* proj_b = (const float*)d_in[7];
  float* out = (float*)d_out;

  char* ws = (char*)d_ws;
  // byte offsets (all 256-aligned)
  u16* xb     = (u16*)(ws + 0);                       //  8 MB  [4096][1024]
  u16* wqkvT  = (u16*)(ws + 8388608);                 //  6 MB  [3072][1024]
  u16* wprojT = (u16*)(ws + 14680064);                //  2 MB  [1024][1024]
  u16* Qh     = (u16*)(ws + 16777216);                //  8 MB  [32][2048][64]
  u16* Kh     = (u16*)(ws + 25165824);                //  8 MB
  u16* Vh     = (u16*)(ws + 33554432);                //  8 MB
  u16* Vt     = (u16*)(ws + 41943040);                //  8 MB  [32][64][2048]
  u16* attnO  = xb;                                   // reuse (xb dead after QKV GEMM)

  k_cast_bf16<<<4096, 256, 0, stream>>>(x, xb, (BN_ * C_) / 4);
  k_transpose_cast<<<dim3(96, 32), dim3(32, 8), 0, stream>>>(qkv_w, wqkvT, C_, 3 * C_);
  k_transpose_cast<<<dim3(32, 32), dim3(32, 8), 0, stream>>>(proj_w, wprojT, C_, C_);
  k_gemm_qkv_ln<<<dim3(24, 32), 256, 0, stream>>>(xb, wqkvT, q_g, q_b, k_g, k_b, Qh, Kh, Vh);
  k_transpose_v<<<dim3(32, 32), dim3(64, 8), 0, stream>>>(Vh, Vt);
  k_attn<<<dim3(16, 32), 256, 0, stream>>>(Qh, Kh, Vt, attnO);
  k_gemm_proj<<<dim3(8, 32), 256, 0, stream>>>(attnO, wprojT, out, proj_b, BN_, C_, C_);
}

// Round 8
// 158.158 us; speedup vs baseline: 1.7897x; 1.0134x over previous
//
#include <hip/hip_runtime.h>

typedef unsigned short u16;
typedef unsigned int u32;
typedef float f32x4 __attribute__((ext_vector_type(4)));
typedef float f32x16 __attribute__((ext_vector_type(16)));
typedef short s16x8 __attribute__((ext_vector_type(8)));

#define B_ 2
#define N_ 2048
#define C_ 1024
#define H_ 16
#define BN_ (B_*N_)   // 4096 rows

#define EXP2F(x) __builtin_amdgcn_exp2f(x)   // v_exp_f32 (base-2 native)

// ---------- helpers ----------
__device__ __forceinline__ u16 f2bf(float f) {
  union { float f; unsigned u; } c; c.f = f;
  unsigned u = c.u;
  u = (u + 0x7fffu + ((u >> 16) & 1u)) >> 16;   // RNE
  return (u16)u;
}
__device__ __forceinline__ float bf2f(u16 h) {
  union { unsigned u; float f; } c; c.u = ((unsigned)h) << 16;
  return c.f;
}
// pack two f32 -> u32 of 2 bf16 via HW cvt (lo16 = src0, hi16 = src1; RNE)
__device__ __forceinline__ u32 pack2(float lo, float hi) {
  u32 r;
  asm("v_cvt_pk_bf16_f32 %0, %1, %2" : "=v"(r) : "v"(lo), "v"(hi));
  return r;
}
__device__ __forceinline__ void gload16(const u16* g, u16* l) {
  __builtin_amdgcn_global_load_lds(
      (const __attribute__((address_space(1))) unsigned*)g,
      (__attribute__((address_space(3))) unsigned*)l, 16, 0, 0);
}

// ---------- fp32 -> bf16 cast (vectorized) ----------
__global__ __launch_bounds__(256) void k_cast_bf16(const float* __restrict__ x,
                                                   u16* __restrict__ o, int n4) {
  int i = blockIdx.x * blockDim.x + threadIdx.x;
  if (i >= n4) return;
  float4 v = ((const float4*)x)[i];
  ushort4 r;
  r.x = f2bf(v.x); r.y = f2bf(v.y); r.z = f2bf(v.z); r.w = f2bf(v.w);
  ((ushort4*)o)[i] = r;
}

// ---------- fp32 [R][C] -> bf16 [C][R] transpose+cast ----------
__global__ __launch_bounds__(256) void k_transpose_cast(const float* __restrict__ W,
                                                        u16* __restrict__ Wt,
                                                        int R, int Cc) {
  __shared__ float t[32][33];
  int tx = threadIdx.x, ty = threadIdx.y;
  int c0 = blockIdx.x * 32, r0 = blockIdx.y * 32;
#pragma unroll
  for (int i = 0; i < 4; ++i)
    t[ty + i * 8][tx] = W[(long)(r0 + ty + i * 8) * Cc + c0 + tx];
  __syncthreads();
#pragma unroll
  for (int i = 0; i < 4; ++i)
    Wt[(long)(c0 + ty + i * 8) * R + r0 + tx] = f2bf(t[tx][ty + i * 8]);
}

// ---------- QKV GEMM with fused per-head LayerNorm epilogue ----------
// Writes Qh scaled by (1/8)*log2(e) so attention can use exp2 directly.
__global__ __launch_bounds__(256) void k_gemm_qkv_ln(const u16* __restrict__ A,
                                                     const u16* __restrict__ Bt,
                                                     const float* __restrict__ qg,
                                                     const float* __restrict__ qbeta,
                                                     const float* __restrict__ kg,
                                                     const float* __restrict__ kbeta,
                                                     u16* __restrict__ Qh,
                                                     u16* __restrict__ Kh,
                                                     u16* __restrict__ Vh) {
  const int K = C_;
  __shared__ u16 a_t[128 * 64];
  __shared__ u16 b_t[128 * 64];
  int tid = threadIdx.x;
  int w = tid >> 6, l = tid & 63;
  int l15 = l & 15, lhi = l >> 4;
  int wm = w >> 1, wn = w & 1;
  int rowA = l >> 3, colA = (l & 7) * 8;
  const u16* Ab = A + (long)blockIdx.y * 128 * K;
  const u16* Bb = Bt + (long)blockIdx.x * 128 * K;
  f32x4 acc[4][4];
#pragma unroll
  for (int m = 0; m < 4; ++m)
#pragma unroll
    for (int n = 0; n < 4; ++n)
      acc[m][n] = (f32x4){0.f, 0.f, 0.f, 0.f};

  for (int k0 = 0; k0 < K; k0 += 64) {
#pragma unroll
    for (int i = 0; i < 4; ++i) {
      int ci = i * 4 + w;
      gload16(Ab + (long)(ci * 8 + rowA) * K + k0 + colA, &a_t[ci * 8 * 64]);
      gload16(Bb + (long)(ci * 8 + rowA) * K + k0 + colA, &b_t[ci * 8 * 64]);
    }
    __syncthreads();
#pragma unroll
    for (int kk = 0; kk < 2; ++kk) {
      s16x8 af[4], bfr[4];
#pragma unroll
      for (int m = 0; m < 4; ++m)
        af[m] = *(const s16x8*)&a_t[(wm * 64 + m * 16 + l15) * 64 + kk * 32 + lhi * 8];
#pragma unroll
      for (int n = 0; n < 4; ++n)
        bfr[n] = *(const s16x8*)&b_t[(wn * 64 + n * 16 + l15) * 64 + kk * 32 + lhi * 8];
#pragma unroll
      for (int m = 0; m < 4; ++m)
#pragma unroll
        for (int n = 0; n < 4; ++n)
          acc[m][n] = __builtin_amdgcn_mfma_f32_16x16x32_bf16(af[m], bfr[n], acc[m][n], 0, 0, 0);
    }
    __syncthreads();
  }

  // ---- fused epilogue ----
  int cb = blockIdx.x * 128 + wn * 64;   // warp col base (64 cols = 1 head)
  int s = cb >> 10;                      // 0=q 1=k 2=v
  int h = (cb & 1023) >> 6;
  int rowbase = blockIdx.y * 128 + wm * 64;

  if (s == 2) {
#pragma unroll
    for (int m = 0; m < 4; ++m) {
#pragma unroll
      for (int r = 0; r < 4; ++r) {
        int row = rowbase + m * 16 + lhi * 4 + r;
        int b = row >> 11, nn = row & (N_ - 1);
        long ob = ((long)(b * H_ + h) * N_ + nn) * 64;
#pragma unroll
        for (int n = 0; n < 4; ++n)
          Vh[ob + n * 16 + l15] = f2bf(acc[m][n][r]);
      }
    }
  } else {
    const float* g = (s == 0) ? qg : kg;
    const float* be = (s == 0) ? qbeta : kbeta;
    u16* Oh = (s == 0) ? Qh : Kh;
    float sc = (s == 0) ? 0.125f * 1.44269504089f : 1.f;   // fold log2(e) for exp2 softmax
    float gv[4], bv[4];
#pragma unroll
    for (int n = 0; n < 4; ++n) { gv[n] = g[n * 16 + l15]; bv[n] = be[n * 16 + l15]; }
#pragma unroll
    for (int m = 0; m < 4; ++m) {
#pragma unroll
      for (int r = 0; r < 4; ++r) {
        float t = (acc[m][0][r] + acc[m][1][r]) + (acc[m][2][r] + acc[m][3][r]);
        t += __shfl_xor(t, 1); t += __shfl_xor(t, 2);
        t += __shfl_xor(t, 4); t += __shfl_xor(t, 8);
        float mean = t * (1.f / 64.f);
        float v0 = acc[m][0][r] - mean, v1 = acc[m][1][r] - mean;
        float v2 = acc[m][2][r] - mean, v3 = acc[m][3][r] - mean;
        float q2 = (v0 * v0 + v1 * v1) + (v2 * v2 + v3 * v3);
        q2 += __shfl_xor(q2, 1); q2 += __shfl_xor(q2, 2);
        q2 += __shfl_xor(q2, 4); q2 += __shfl_xor(q2, 8);
        float rs = rsqrtf(q2 * (1.f / 64.f) + 1e-6f);
        int row = rowbase + m * 16 + lhi * 4 + r;
        int b = row >> 11, nn = row & (N_ - 1);
        long ob = ((long)(b * H_ + h) * N_ + nn) * 64;
        float vv[4] = {v0, v1, v2, v3};
#pragma unroll
        for (int n = 0; n < 4; ++n)
          Oh[ob + n * 16 + l15] = f2bf(sc * (gv[n] * vv[n] * rs + bv[n]));
      }
    }
  }
}

// ---------- proj GEMM: C[M][N] = A*Bt^T, fp32 out + bias ----------
__global__ __launch_bounds__(256) void k_gemm_proj(const u16* __restrict__ A,
                                                   const u16* __restrict__ Bt,
                                                   float* __restrict__ Cout,
                                                   const float* __restrict__ bias,
                                                   int M, int N, int K) {
  __shared__ u16 a_t[128 * 64];
  __shared__ u16 b_t[128 * 64];
  int tid = threadIdx.x;
  int w = tid >> 6, l = tid & 63;
  int l15 = l & 15, lhi = l >> 4;
  int wm = w >> 1, wn = w & 1;
  int rowA = l >> 3, colA = (l & 7) * 8;
  const u16* Ab = A + (long)blockIdx.y * 128 * K;
  const u16* Bb = Bt + (long)blockIdx.x * 128 * K;
  f32x4 acc[4][4];
#pragma unroll
  for (int m = 0; m < 4; ++m)
#pragma unroll
    for (int n = 0; n < 4; ++n)
      acc[m][n] = (f32x4){0.f, 0.f, 0.f, 0.f};

  for (int k0 = 0; k0 < K; k0 += 64) {
#pragma unroll
    for (int i = 0; i < 4; ++i) {
      int ci = i * 4 + w;
      gload16(Ab + (long)(ci * 8 + rowA) * K + k0 + colA, &a_t[ci * 8 * 64]);
      gload16(Bb + (long)(ci * 8 + rowA) * K + k0 + colA, &b_t[ci * 8 * 64]);
    }
    __syncthreads();
#pragma unroll
    for (int kk = 0; kk < 2; ++kk) {
      s16x8 af[4], bfr[4];
#pragma unroll
      for (int m = 0; m < 4; ++m)
        af[m] = *(const s16x8*)&a_t[(wm * 64 + m * 16 + l15) * 64 + kk * 32 + lhi * 8];
#pragma unroll
      for (int n = 0; n < 4; ++n)
        bfr[n] = *(const s16x8*)&b_t[(wn * 64 + n * 16 + l15) * 64 + kk * 32 + lhi * 8];
#pragma unroll
      for (int m = 0; m < 4; ++m)
#pragma unroll
        for (int n = 0; n < 4; ++n)
          acc[m][n] = __builtin_amdgcn_mfma_f32_16x16x32_bf16(af[m], bfr[n], acc[m][n], 0, 0, 0);
    }
    __syncthreads();
  }
#pragma unroll
  for (int m = 0; m < 4; ++m) {
#pragma unroll
    for (int n = 0; n < 4; ++n) {
      int col = blockIdx.x * 128 + wn * 64 + n * 16 + l15;
#pragma unroll
      for (int r = 0; r < 4; ++r) {
        int row = blockIdx.y * 128 + wm * 64 + m * 16 + lhi * 4 + r;
        Cout[(long)row * N + col] = acc[m][n][r] + bias[col];
      }
    }
  }
}

// ---------- V [bh][N][64] -> Vt [bh][64][N] (bf16 transpose) ----------
__global__ __launch_bounds__(512) void k_transpose_v(const u16* __restrict__ Vh,
                                                     u16* __restrict__ Vt) {
  __shared__ u16 t[64][65];
  int tx = threadIdx.x, ty = threadIdx.y;  // (64,8)
  int bh = blockIdx.y;
  int n0 = blockIdx.x * 64;
#pragma unroll
  for (int i = 0; i < 8; ++i)
    t[ty + i * 8][tx] = Vh[((long)bh * N_ + n0 + ty + i * 8) * 64 + tx];
  __syncthreads();
#pragma unroll
  for (int i = 0; i < 8; ++i)
    Vt[((long)bh * 64 + ty + i * 8) * N_ + n0 + tx] = t[tx][ty + i * 8];
}

// ---------- flash attention: swapped-QK^T 32x32 + in-register softmax ----------
// Qh pre-scaled by (1/8)*log2(e) -> softmax uses exp2 (v_exp_f32 native).
// 3-buffer K/V LDS pipeline with counted vmcnt (T4): per wave each stage = 4
// global_load_lds ops; at tile t wait own vmcnt(4) (tile t's loads landed,
// t+1's may fly), barrier, issue stage(t+2), compute. Loads are never
// drained to 0 mid-loop. setprio(1) wraps the MFMA clusters (T5).
__global__ __launch_bounds__(256, 2) void k_attn(const u16* __restrict__ Qh,
                                                 const u16* __restrict__ Kh,
                                                 const u16* __restrict__ Vt,
                                                 u16* __restrict__ O) {
  __shared__ u16 k_t[3][64 * 64];
  __shared__ u16 v_t[3][64 * 64];
  int tid = threadIdx.x;
  int w = tid >> 6, l = tid & 63;
  int l31 = l & 31, hi = l >> 5;
  int qb = blockIdx.x, bh = blockIdx.y;
  int b = bh >> 4, h = bh & 15;
  const u16* Qb = Qh + ((long)bh * N_ + qb * 128 + w * 32) * 64;
  const u16* Kb = Kh + (long)bh * N_ * 64;
  const u16* Vb = Vt + (long)bh * 64 * N_;

  // Q as B-operand fragments: B[k=d][col=q=lane&31], d = j*16 + hi*8 + e
  s16x8 qf[4];
#pragma unroll
  for (int j = 0; j < 4; ++j)
    qf[j] = *(const s16x8*)&Qb[l31 * 64 + j * 16 + hi * 8];

  f32x16 acc0, acc1;
#pragma unroll
  for (int i = 0; i < 16; ++i) { acc0[i] = 0.f; acc1[i] = 0.f; }
  float m = -3e38f, lsum = 0.f;

  // fragment read offsets: row (t*32+l31), 16B slot (j*2+hi)^(l&7)
  int off[2][4];
#pragma unroll
  for (int t = 0; t < 2; ++t)
#pragma unroll
    for (int j = 0; j < 4; ++j)
      off[t][j] = (t * 32 + l31) * 64 + (((j * 2 + hi) ^ (l & 7)) * 8);

  // staging geometry (8-row stripes, pre-swizzled source column)
  int srow = l >> 3;
  int scol = ((l & 7) ^ srow) * 8;

  auto STAGE = [&](int kt, int bi) {
#pragma unroll
    for (int i = 0; i < 2; ++i) {
      int ci = i * 4 + w;
      gload16(Kb + (long)(kt + ci * 8 + srow) * 64 + scol, &k_t[bi][ci * 512]);
      gload16(Vb + (long)(ci * 8 + srow) * N_ + kt + scol, &v_t[bi][ci * 512]);
    }
  };

  const int NT = N_ / 64;  // 32
  STAGE(0, 0);
  STAGE(64, 1);

  int cb = 0;
  for (int t = 0; t < NT; ++t) {
    if (t + 1 < NT) asm volatile("s_waitcnt vmcnt(4)" ::: "memory");
    else            asm volatile("s_waitcnt vmcnt(0)" ::: "memory");
    __builtin_amdgcn_s_barrier();
    if (t + 2 < NT) {
      int sb = cb + 2; if (sb >= 3) sb -= 3;
      STAGE((t + 2) * 64, sb);
    }
    const u16* kb = k_t[cb];
    const u16* vb = v_t[cb];

    // ---- S^T = mfma(K, Q): lane q=l31; s0 = keys 0..31, s1 = keys 32..63 ----
    f32x16 s0, s1;
#pragma unroll
    for (int i = 0; i < 16; ++i) { s0[i] = 0.f; s1[i] = 0.f; }
    __builtin_amdgcn_s_setprio(1);
#pragma unroll
    for (int j = 0; j < 4; ++j) {
      s16x8 kf0 = *(const s16x8*)&kb[off[0][j]];
      s0 = __builtin_amdgcn_mfma_f32_32x32x16_bf16(kf0, qf[j], s0, 0, 0, 0);
      s16x8 kf1 = *(const s16x8*)&kb[off[1][j]];
      s1 = __builtin_amdgcn_mfma_f32_32x32x16_bf16(kf1, qf[j], s1, 0, 0, 0);
    }
    __builtin_amdgcn_s_setprio(0);

    // ---- row max: in-lane tree + one cross-half exchange ----
    f32x16 mx;
#pragma unroll
    for (int i = 0; i < 16; ++i) mx[i] = fmaxf(s0[i], s1[i]);
#pragma unroll
    for (int i = 0; i < 8; ++i) mx[i] = fmaxf(mx[i], mx[i + 8]);
#pragma unroll
    for (int i = 0; i < 4; ++i) mx[i] = fmaxf(mx[i], mx[i + 4]);
    float pm = fmaxf(fmaxf(mx[0], mx[1]), fmaxf(mx[2], mx[3]));
    pm = fmaxf(pm, __shfl_xor(pm, 32));

    // ---- defer-max rescale (rare; wave-uniform branch); log2 domain ----
    if (__ballot(pm > m + 11.5f)) {
      float mnew = fmaxf(m, pm);
      float alpha = EXP2F(m - mnew);
      m = mnew;
      lsum *= alpha;
      int ai = __float_as_int(alpha);
#pragma unroll
      for (int r = 0; r < 16; ++r) {
        int ql = (r & 3) + 8 * (r >> 2) + 4 * hi;
        float ar = __int_as_float(__builtin_amdgcn_ds_bpermute(ql << 2, ai));
        acc0[r] *= ar;
        acc1[r] *= ar;
      }
    }

    // ---- P = exp2(S - m), row sum ----
#pragma unroll
    for (int i = 0; i < 16; ++i) {
      s0[i] = EXP2F(s0[i] - m);
      s1[i] = EXP2F(s1[i] - m);
    }
    f32x16 sm;
#pragma unroll
    for (int i = 0; i < 16; ++i) sm[i] = s0[i] + s1[i];
#pragma unroll
    for (int i = 0; i < 8; ++i) sm[i] += sm[i + 8];
#pragma unroll
    for (int i = 0; i < 4; ++i) sm[i] += sm[i + 4];
    float rs = (sm[0] + sm[1]) + (sm[2] + sm[3]);
    lsum += rs + __shfl_xor(rs, 32);

    // ---- pack P into PV A-fragments ----
    s16x8 pa[4];
#pragma unroll
    for (int g = 0; g < 4; ++g) {
      const f32x16& sv = (g < 2) ? s0 : s1;
      int o = (g & 1) * 8;
      u32 w01 = pack2(sv[o + 0], sv[o + 1]);
      u32 w23 = pack2(sv[o + 2], sv[o + 3]);
      u32 w45 = pack2(sv[o + 4], sv[o + 5]);
      u32 w67 = pack2(sv[o + 6], sv[o + 7]);
      u32 recvA = __shfl_xor(hi ? w01 : w45, 32);
      u32 recvB = __shfl_xor(hi ? w23 : w67, 32);
      union { u32 u[4]; s16x8 v; } fr;
      fr.u[0] = hi ? recvA : w01;
      fr.u[1] = hi ? recvB : w23;
      fr.u[2] = hi ? w45 : recvA;
      fr.u[3] = hi ? w67 : recvB;
      pa[g] = fr.v;
    }

    // ---- O += P V : acc0 = d 0..31, acc1 = d 32..63 ----
    __builtin_amdgcn_s_setprio(1);
#pragma unroll
    for (int j = 0; j < 4; ++j) {
      s16x8 vf0 = *(const s16x8*)&vb[off[0][j]];
      acc0 = __builtin_amdgcn_mfma_f32_32x32x16_bf16(pa[j], vf0, acc0, 0, 0, 0);
      s16x8 vf1 = *(const s16x8*)&vb[off[1][j]];
      acc1 = __builtin_amdgcn_mfma_f32_32x32x16_bf16(pa[j], vf1, acc1, 0, 0, 0);
    }
    __builtin_amdgcn_s_setprio(0);
    cb = (cb + 1 == 3) ? 0 : cb + 1;
  }

  // ---- epilogue: O[b][q][h*64+d] = acc / lsum[q] ----
  int li = __float_as_int(lsum);
#pragma unroll
  for (int r = 0; r < 16; ++r) {
    int ql = (r & 3) + 8 * (r >> 2) + 4 * hi;
    float ls = __int_as_float(__builtin_amdgcn_ds_bpermute(ql << 2, li));
    float inv = 1.f / ls;
    int q = qb * 128 + w * 32 + ql;
    long ob = ((long)(b * N_ + q) * H_ + h) * 64 + l31;
    O[ob] = f2bf(acc0[r] * inv);
    O[ob + 32] = f2bf(acc1[r] * inv);
  }
}

// ---------- launch ----------
extern "C" void kernel_launch(void* const* d_in, const int* in_sizes, int n_in,
                              void* d_out, int out_size, void* d_ws, size_t ws_size,
                              hipStream_t stream) {
  const float* x      = (const float*)d_in[0];
  const float* qkv_w  = (const float*)d_in[1];
  const float* q_g    = (const float*)d_in[2];
  const float* q_b    = (const float*)d_in[3];
  const float* k_g    = (const float*)d_in[4];
  const float* k_b    = (const float*)d_in[5];
  const float* proj_w = (const float*)d_in[6];
  const float* proj_b = (const float*)d_in[7];
  float* out = (float*)d_out;

  char* ws = (char*)d_ws;
  // byte offsets (all 256-aligned)
  u16* xb     = (u16*)(ws + 0);                       //  8 MB  [4096][1024]
  u16* wqkvT  = (u16*)(ws + 8388608);                 //  6 MB  [3072][1024]
  u16* wprojT = (u16*)(ws + 14680064);                //  2 MB  [1024][1024]
  u16* Qh     = (u16*)(ws + 16777216);                //  8 MB  [32][2048][64]
  u16* Kh     = (u16*)(ws + 25165824);                //  8 MB
  u16* Vh     = (u16*)(ws + 33554432);                //  8 MB
  u16* Vt     = (u16*)(ws + 41943040);                //  8 MB  [32][64][2048]
  u16* attnO  = xb;                                   // reuse (xb dead after QKV GEMM)

  k_cast_bf16<<<4096, 256, 0, stream>>>(x, xb, (BN_ * C_) / 4);
  k_transpose_cast<<<dim3(96, 32), dim3(32, 8), 0, stream>>>(qkv_w, wqkvT, C_, 3 * C_);
  k_transpose_cast<<<dim3(32, 32), dim3(32, 8), 0, stream>>>(proj_w, wprojT, C_, C_);
  k_gemm_qkv_ln<<<dim3(24, 32), 256, 0, stream>>>(xb, wqkvT, q_g, q_b, k_g, k_b, Qh, Kh, Vh);
  k_transpose_v<<<dim3(32, 32), dim3(64, 8), 0, stream>>>(Vh, Vt);
  k_attn<<<dim3(16, 32), 256, 0, stream>>>(Qh, Kh, Vt, attnO);
  k_gemm_proj<<<dim3(8, 32), 256, 0, stream>>>(attnO, wprojT, out, proj_b, BN_, C_, C_);
}

// Round 9
// 153.125 us; speedup vs baseline: 1.8485x; 1.0329x over previous
//
#include <hip/hip_runtime.h>

typedef unsigned short u16;
typedef unsigned int u32;
typedef float f32x4 __attribute__((ext_vector_type(4)));
typedef float f32x16 __attribute__((ext_vector_type(16)));
typedef short s16x8 __attribute__((ext_vector_type(8)));

#define B_ 2
#define N_ 2048
#define C_ 1024
#define H_ 16
#define BN_ (B_*N_)   // 4096 rows

#define EXP2F(x) __builtin_amdgcn_exp2f(x)   // v_exp_f32 (base-2 native)

// ---------- helpers ----------
__device__ __forceinline__ u16 f2bf(float f) {
  union { float f; unsigned u; } c; c.f = f;
  unsigned u = c.u;
  u = (u + 0x7fffu + ((u >> 16) & 1u)) >> 16;   // RNE
  return (u16)u;
}
__device__ __forceinline__ float bf2f(u16 h) {
  union { unsigned u; float f; } c; c.u = ((unsigned)h) << 16;
  return c.f;
}
// pack two f32 -> u32 of 2 bf16 via HW cvt (lo16 = src0, hi16 = src1; RNE)
__device__ __forceinline__ u32 pack2(float lo, float hi) {
  u32 r;
  asm("v_cvt_pk_bf16_f32 %0, %1, %2" : "=v"(r) : "v"(lo), "v"(hi));
  return r;
}
__device__ __forceinline__ void gload16(const u16* g, u16* l) {
  __builtin_amdgcn_global_load_lds(
      (const __attribute__((address_space(1))) unsigned*)g,
      (__attribute__((address_space(3))) unsigned*)l, 16, 0, 0);
}

// ---------- fp32 -> bf16 cast (vectorized) ----------
__global__ __launch_bounds__(256) void k_cast_bf16(const float* __restrict__ x,
                                                   u16* __restrict__ o, int n4) {
  int i = blockIdx.x * blockDim.x + threadIdx.x;
  if (i >= n4) return;
  float4 v = ((const float4*)x)[i];
  ushort4 r;
  r.x = f2bf(v.x); r.y = f2bf(v.y); r.z = f2bf(v.z); r.w = f2bf(v.w);
  ((ushort4*)o)[i] = r;
}

// ---------- fp32 [R][C] -> bf16 [C][R] transpose+cast ----------
__global__ __launch_bounds__(256) void k_transpose_cast(const float* __restrict__ W,
                                                        u16* __restrict__ Wt,
                                                        int R, int Cc) {
  __shared__ float t[32][33];
  int tx = threadIdx.x, ty = threadIdx.y;
  int c0 = blockIdx.x * 32, r0 = blockIdx.y * 32;
#pragma unroll
  for (int i = 0; i < 4; ++i)
    t[ty + i * 8][tx] = W[(long)(r0 + ty + i * 8) * Cc + c0 + tx];
  __syncthreads();
#pragma unroll
  for (int i = 0; i < 4; ++i)
    Wt[(long)(c0 + ty + i * 8) * R + r0 + tx] = f2bf(t[tx][ty + i * 8]);
}

// ---------- QKV GEMM with fused per-head LayerNorm epilogue ----------
// Writes Qh scaled by (1/8)*log2(e) so attention can use exp2 directly.
__global__ __launch_bounds__(256) void k_gemm_qkv_ln(const u16* __restrict__ A,
                                                     const u16* __restrict__ Bt,
                                                     const float* __restrict__ qg,
                                                     const float* __restrict__ qbeta,
                                                     const float* __restrict__ kg,
                                                     const float* __restrict__ kbeta,
                                                     u16* __restrict__ Qh,
                                                     u16* __restrict__ Kh,
                                                     u16* __restrict__ Vh) {
  const int K = C_;
  __shared__ u16 a_t[128 * 64];
  __shared__ u16 b_t[128 * 64];
  int tid = threadIdx.x;
  int w = tid >> 6, l = tid & 63;
  int l15 = l & 15, lhi = l >> 4;
  int wm = w >> 1, wn = w & 1;
  int rowA = l >> 3, colA = (l & 7) * 8;
  const u16* Ab = A + (long)blockIdx.y * 128 * K;
  const u16* Bb = Bt + (long)blockIdx.x * 128 * K;
  f32x4 acc[4][4];
#pragma unroll
  for (int m = 0; m < 4; ++m)
#pragma unroll
    for (int n = 0; n < 4; ++n)
      acc[m][n] = (f32x4){0.f, 0.f, 0.f, 0.f};

  for (int k0 = 0; k0 < K; k0 += 64) {
#pragma unroll
    for (int i = 0; i < 4; ++i) {
      int ci = i * 4 + w;
      gload16(Ab + (long)(ci * 8 + rowA) * K + k0 + colA, &a_t[ci * 8 * 64]);
      gload16(Bb + (long)(ci * 8 + rowA) * K + k0 + colA, &b_t[ci * 8 * 64]);
    }
    __syncthreads();
#pragma unroll
    for (int kk = 0; kk < 2; ++kk) {
      s16x8 af[4], bfr[4];
#pragma unroll
      for (int m = 0; m < 4; ++m)
        af[m] = *(const s16x8*)&a_t[(wm * 64 + m * 16 + l15) * 64 + kk * 32 + lhi * 8];
#pragma unroll
      for (int n = 0; n < 4; ++n)
        bfr[n] = *(const s16x8*)&b_t[(wn * 64 + n * 16 + l15) * 64 + kk * 32 + lhi * 8];
#pragma unroll
      for (int m = 0; m < 4; ++m)
#pragma unroll
        for (int n = 0; n < 4; ++n)
          acc[m][n] = __builtin_amdgcn_mfma_f32_16x16x32_bf16(af[m], bfr[n], acc[m][n], 0, 0, 0);
    }
    __syncthreads();
  }

  // ---- fused epilogue ----
  int cb = blockIdx.x * 128 + wn * 64;   // warp col base (64 cols = 1 head)
  int s = cb >> 10;                      // 0=q 1=k 2=v
  int h = (cb & 1023) >> 6;
  int rowbase = blockIdx.y * 128 + wm * 64;

  if (s == 2) {
#pragma unroll
    for (int m = 0; m < 4; ++m) {
#pragma unroll
      for (int r = 0; r < 4; ++r) {
        int row = rowbase + m * 16 + lhi * 4 + r;
        int b = row >> 11, nn = row & (N_ - 1);
        long ob = ((long)(b * H_ + h) * N_ + nn) * 64;
#pragma unroll
        for (int n = 0; n < 4; ++n)
          Vh[ob + n * 16 + l15] = f2bf(acc[m][n][r]);
      }
    }
  } else {
    const float* g = (s == 0) ? qg : kg;
    const float* be = (s == 0) ? qbeta : kbeta;
    u16* Oh = (s == 0) ? Qh : Kh;
    float sc = (s == 0) ? 0.125f * 1.44269504089f : 1.f;   // fold log2(e) for exp2 softmax
    float gv[4], bv[4];
#pragma unroll
    for (int n = 0; n < 4; ++n) { gv[n] = g[n * 16 + l15]; bv[n] = be[n * 16 + l15]; }
#pragma unroll
    for (int m = 0; m < 4; ++m) {
#pragma unroll
      for (int r = 0; r < 4; ++r) {
        float t = (acc[m][0][r] + acc[m][1][r]) + (acc[m][2][r] + acc[m][3][r]);
        t += __shfl_xor(t, 1); t += __shfl_xor(t, 2);
        t += __shfl_xor(t, 4); t += __shfl_xor(t, 8);
        float mean = t * (1.f / 64.f);
        float v0 = acc[m][0][r] - mean, v1 = acc[m][1][r] - mean;
        float v2 = acc[m][2][r] - mean, v3 = acc[m][3][r] - mean;
        float q2 = (v0 * v0 + v1 * v1) + (v2 * v2 + v3 * v3);
        q2 += __shfl_xor(q2, 1); q2 += __shfl_xor(q2, 2);
        q2 += __shfl_xor(q2, 4); q2 += __shfl_xor(q2, 8);
        float rs = rsqrtf(q2 * (1.f / 64.f) + 1e-6f);
        int row = rowbase + m * 16 + lhi * 4 + r;
        int b = row >> 11, nn = row & (N_ - 1);
        long ob = ((long)(b * H_ + h) * N_ + nn) * 64;
        float vv[4] = {v0, v1, v2, v3};
#pragma unroll
        for (int n = 0; n < 4; ++n)
          Oh[ob + n * 16 + l15] = f2bf(sc * (gv[n] * vv[n] * rs + bv[n]));
      }
    }
  }
}

// ---------- proj GEMM: C[M][N] = A*Bt^T, fp32 out + bias ----------
__global__ __launch_bounds__(256) void k_gemm_proj(const u16* __restrict__ A,
                                                   const u16* __restrict__ Bt,
                                                   float* __restrict__ Cout,
                                                   const float* __restrict__ bias,
                                                   int M, int N, int K) {
  __shared__ u16 a_t[128 * 64];
  __shared__ u16 b_t[128 * 64];
  int tid = threadIdx.x;
  int w = tid >> 6, l = tid & 63;
  int l15 = l & 15, lhi = l >> 4;
  int wm = w >> 1, wn = w & 1;
  int rowA = l >> 3, colA = (l & 7) * 8;
  const u16* Ab = A + (long)blockIdx.y * 128 * K;
  const u16* Bb = Bt + (long)blockIdx.x * 128 * K;
  f32x4 acc[4][4];
#pragma unroll
  for (int m = 0; m < 4; ++m)
#pragma unroll
    for (int n = 0; n < 4; ++n)
      acc[m][n] = (f32x4){0.f, 0.f, 0.f, 0.f};

  for (int k0 = 0; k0 < K; k0 += 64) {
#pragma unroll
    for (int i = 0; i < 4; ++i) {
      int ci = i * 4 + w;
      gload16(Ab + (long)(ci * 8 + rowA) * K + k0 + colA, &a_t[ci * 8 * 64]);
      gload16(Bb + (long)(ci * 8 + rowA) * K + k0 + colA, &b_t[ci * 8 * 64]);
    }
    __syncthreads();
#pragma unroll
    for (int kk = 0; kk < 2; ++kk) {
      s16x8 af[4], bfr[4];
#pragma unroll
      for (int m = 0; m < 4; ++m)
        af[m] = *(const s16x8*)&a_t[(wm * 64 + m * 16 + l15) * 64 + kk * 32 + lhi * 8];
#pragma unroll
      for (int n = 0; n < 4; ++n)
        bfr[n] = *(const s16x8*)&b_t[(wn * 64 + n * 16 + l15) * 64 + kk * 32 + lhi * 8];
#pragma unroll
      for (int m = 0; m < 4; ++m)
#pragma unroll
        for (int n = 0; n < 4; ++n)
          acc[m][n] = __builtin_amdgcn_mfma_f32_16x16x32_bf16(af[m], bfr[n], acc[m][n], 0, 0, 0);
    }
    __syncthreads();
  }
#pragma unroll
  for (int m = 0; m < 4; ++m) {
#pragma unroll
    for (int n = 0; n < 4; ++n) {
      int col = blockIdx.x * 128 + wn * 64 + n * 16 + l15;
#pragma unroll
      for (int r = 0; r < 4; ++r) {
        int row = blockIdx.y * 128 + wm * 64 + m * 16 + lhi * 4 + r;
        Cout[(long)row * N + col] = acc[m][n][r] + bias[col];
      }
    }
  }
}

// ---------- V [bh][N][64] -> Vt [bh][64][N] (bf16 transpose) ----------
__global__ __launch_bounds__(512) void k_transpose_v(const u16* __restrict__ Vh,
                                                     u16* __restrict__ Vt) {
  __shared__ u16 t[64][65];
  int tx = threadIdx.x, ty = threadIdx.y;  // (64,8)
  int bh = blockIdx.y;
  int n0 = blockIdx.x * 64;
#pragma unroll
  for (int i = 0; i < 8; ++i)
    t[ty + i * 8][tx] = Vh[((long)bh * N_ + n0 + ty + i * 8) * 64 + tx];
  __syncthreads();
#pragma unroll
  for (int i = 0; i < 8; ++i)
    Vt[((long)bh * 64 + ty + i * 8) * N_ + n0 + tx] = t[tx][ty + i * 8];
}

// ---------- flash attention: 8-wave block, in-block KV split ----------
// Qh pre-scaled by (1/8)*log2(e); softmax in exp2 domain.
// Waves 0-3 (half 0) process keys 0..1023; waves 4-7 (half 1) keys 1024..2047;
// both cover the same 128 q-rows (wave wq = w&3 owns q-rows wq*32..wq*32+31).
// Per-half 2-buffer LDS pipeline, counted vmcnt(4) (never drains mid-loop),
// 2 barriers/iter. End: online-softmax merge of the two halves through LDS
// (B-half writes m/lsum/acc; A-half combines + writes O). 64KB LDS ->
// 2 blocks/CU = 16 waves/CU (VGPR<=128 via __launch_bounds__(512,4)).
__global__ __launch_bounds__(512, 4) void k_attn(const u16* __restrict__ Qh,
                                                 const u16* __restrict__ Kh,
                                                 const u16* __restrict__ Vt,
                                                 u16* __restrict__ O) {
  __shared__ u16 k_t[2][2][64 * 64];   // [half][buf][.]  32KB
  __shared__ u16 v_t[2][2][64 * 64];   //                 32KB
  int tid = threadIdx.x;
  int w = tid >> 6, l = tid & 63;
  int half = w >> 2, wq = w & 3;
  int l31 = l & 31, hi = l >> 5;
  int qb = blockIdx.x, bh = blockIdx.y;
  int b = bh >> 4, h = bh & 15;
  const u16* Qb = Qh + ((long)bh * N_ + qb * 128 + wq * 32) * 64;
  const u16* Kb = Kh + ((long)bh * N_ + half * 1024) * 64;
  const u16* Vb = Vt + (long)bh * 64 * N_ + half * 1024;

  // Q as B-operand fragments: B[k=d][col=q=lane&31], d = j*16 + hi*8 + e
  s16x8 qf[4];
#pragma unroll
  for (int j = 0; j < 4; ++j)
    qf[j] = *(const s16x8*)&Qb[l31 * 64 + j * 16 + hi * 8];

  f32x16 acc0, acc1;
#pragma unroll
  for (int i = 0; i < 16; ++i) { acc0[i] = 0.f; acc1[i] = 0.f; }
  float m = -3e38f, lsum = 0.f;

  // fragment read offsets: row (t*32+l31), 16B slot (j*2+hi)^(l&7)
  int off[2][4];
#pragma unroll
  for (int t = 0; t < 2; ++t)
#pragma unroll
    for (int j = 0; j < 4; ++j)
      off[t][j] = (t * 32 + l31) * 64 + (((j * 2 + hi) ^ (l & 7)) * 8);

  // staging geometry (8-row stripes, pre-swizzled source column)
  int srow = l >> 3;
  int scol = ((l & 7) ^ srow) * 8;

  auto STAGE = [&](int kt, int bi) {
#pragma unroll
    for (int i = 0; i < 2; ++i) {
      int ci = i * 4 + wq;
      gload16(Kb + (long)(kt + ci * 8 + srow) * 64 + scol, &k_t[half][bi][ci * 512]);
      gload16(Vb + (long)(ci * 8 + srow) * N_ + kt + scol, &v_t[half][bi][ci * 512]);
    }
  };

  const int NT = 16;   // 1024 keys per half / 64
  STAGE(0, 0);

  for (int t = 0; t < NT; ++t) {
    __builtin_amdgcn_s_barrier();          // A: everyone done computing t-1
    if (t + 1 < NT) {
      STAGE((t + 1) * 64, (t + 1) & 1);
      asm volatile("s_waitcnt vmcnt(4)" ::: "memory");
    } else {
      asm volatile("s_waitcnt vmcnt(0)" ::: "memory");
    }
    __builtin_amdgcn_s_barrier();          // B: tile t staged for all waves
    const u16* kb = k_t[half][t & 1];
    const u16* vb = v_t[half][t & 1];

    // ---- S^T = mfma(K, Q): lane q=l31; s0 = keys 0..31, s1 = keys 32..63 ----
    f32x16 s0, s1;
#pragma unroll
    for (int i = 0; i < 16; ++i) { s0[i] = 0.f; s1[i] = 0.f; }
    __builtin_amdgcn_s_setprio(1);
#pragma unroll
    for (int j = 0; j < 4; ++j) {
      s16x8 kf0 = *(const s16x8*)&kb[off[0][j]];
      s0 = __builtin_amdgcn_mfma_f32_32x32x16_bf16(kf0, qf[j], s0, 0, 0, 0);
      s16x8 kf1 = *(const s16x8*)&kb[off[1][j]];
      s1 = __builtin_amdgcn_mfma_f32_32x32x16_bf16(kf1, qf[j], s1, 0, 0, 0);
    }
    __builtin_amdgcn_s_setprio(0);

    // ---- row max: in-lane tree + one cross-half exchange ----
    f32x16 mx;
#pragma unroll
    for (int i = 0; i < 16; ++i) mx[i] = fmaxf(s0[i], s1[i]);
#pragma unroll
    for (int i = 0; i < 8; ++i) mx[i] = fmaxf(mx[i], mx[i + 8]);
#pragma unroll
    for (int i = 0; i < 4; ++i) mx[i] = fmaxf(mx[i], mx[i + 4]);
    float pm = fmaxf(fmaxf(mx[0], mx[1]), fmaxf(mx[2], mx[3]));
    pm = fmaxf(pm, __shfl_xor(pm, 32));

    // ---- defer-max rescale (rare; wave-uniform branch); log2 domain ----
    if (__ballot(pm > m + 11.5f)) {
      float mnew = fmaxf(m, pm);
      float alpha = EXP2F(m - mnew);
      m = mnew;
      lsum *= alpha;
      int ai = __float_as_int(alpha);
#pragma unroll
      for (int r = 0; r < 16; ++r) {
        int ql = (r & 3) + 8 * (r >> 2) + 4 * hi;
        float ar = __int_as_float(__builtin_amdgcn_ds_bpermute(ql << 2, ai));
        acc0[r] *= ar;
        acc1[r] *= ar;
      }
    }

    // ---- P = exp2(S - m), row sum ----
#pragma unroll
    for (int i = 0; i < 16; ++i) {
      s0[i] = EXP2F(s0[i] - m);
      s1[i] = EXP2F(s1[i] - m);
    }
    f32x16 sm;
#pragma unroll
    for (int i = 0; i < 16; ++i) sm[i] = s0[i] + s1[i];
#pragma unroll
    for (int i = 0; i < 8; ++i) sm[i] += sm[i + 8];
#pragma unroll
    for (int i = 0; i < 4; ++i) sm[i] += sm[i + 4];
    float rs = (sm[0] + sm[1]) + (sm[2] + sm[3]);
    lsum += rs + __shfl_xor(rs, 32);

    // ---- pack P into PV A-fragments ----
    s16x8 pa[4];
#pragma unroll
    for (int g = 0; g < 4; ++g) {
      const f32x16& sv = (g < 2) ? s0 : s1;
      int o = (g & 1) * 8;
      u32 w01 = pack2(sv[o + 0], sv[o + 1]);
      u32 w23 = pack2(sv[o + 2], sv[o + 3]);
      u32 w45 = pack2(sv[o + 4], sv[o + 5]);
      u32 w67 = pack2(sv[o + 6], sv[o + 7]);
      u32 recvA = __shfl_xor(hi ? w01 : w45, 32);
      u32 recvB = __shfl_xor(hi ? w23 : w67, 32);
      union { u32 u[4]; s16x8 v; } fr;
      fr.u[0] = hi ? recvA : w01;
      fr.u[1] = hi ? recvB : w23;
      fr.u[2] = hi ? w45 : recvA;
      fr.u[3] = hi ? w67 : recvB;
      pa[g] = fr.v;
    }

    // ---- O += P V : acc0 = d 0..31, acc1 = d 32..63 (lane = d, reg = q) ----
    __builtin_amdgcn_s_setprio(1);
#pragma unroll
    for (int j = 0; j < 4; ++j) {
      s16x8 vf0 = *(const s16x8*)&vb[off[0][j]];
      acc0 = __builtin_amdgcn_mfma_f32_32x32x16_bf16(pa[j], vf0, acc0, 0, 0, 0);
      s16x8 vf1 = *(const s16x8*)&vb[off[1][j]];
      acc1 = __builtin_amdgcn_mfma_f32_32x32x16_bf16(pa[j], vf1, acc1, 0, 0, 0);
    }
    __builtin_amdgcn_s_setprio(0);
  }

  // ---- merge the two KV halves through LDS ----
  __syncthreads();   // all compute done; staging LDS reusable
  float* mbuf = (float*)&k_t[0][0][0];     // [4 waves][32 regs][64 lanes] f32 = 32KB
  float* ml   = (float*)&v_t[0][0][0];     // [0..127]=m_b per q, [128..255]=lsum_b

  if (half == 1) {
    if (hi == 0) {
      ml[wq * 32 + l31] = m;
      ml[128 + wq * 32 + l31] = lsum;
    }
#pragma unroll
    for (int r = 0; r < 16; ++r) {
      mbuf[((wq * 32 + r) * 64) + l] = acc0[r];
      mbuf[((wq * 32 + 16 + r) * 64) + l] = acc1[r];
    }
  }
  __syncthreads();

  if (half == 0) {
    float m_b = ml[wq * 32 + l31];
    float s_b = ml[128 + wq * 32 + l31];
    float mstar = fmaxf(m, m_b);
    float aa = EXP2F(m - mstar);
    float ab = EXP2F(m_b - mstar);
    float lstar = lsum * aa + s_b * ab;
    int aai = __float_as_int(aa), abi = __float_as_int(ab);
    int lsi = __float_as_int(lstar);
#pragma unroll
    for (int r = 0; r < 16; ++r) {
      int ql = (r & 3) + 8 * (r >> 2) + 4 * hi;
      float Aa = __int_as_float(__builtin_amdgcn_ds_bpermute(ql << 2, aai));
      float Ab = __int_as_float(__builtin_amdgcn_ds_bpermute(ql << 2, abi));
      float ls = __int_as_float(__builtin_amdgcn_ds_bpermute(ql << 2, lsi));
      float o0 = acc0[r] * Aa + mbuf[((wq * 32 + r) * 64) + l] * Ab;
      float o1 = acc1[r] * Aa + mbuf[((wq * 32 + 16 + r) * 64) + l] * Ab;
      float inv = 1.f / ls;
      int q = qb * 128 + wq * 32 + ql;
      long ob = ((long)(b * N_ + q) * H_ + h) * 64 + l31;
      O[ob] = f2bf(o0 * inv);
      O[ob + 32] = f2bf(o1 * inv);
    }
  }
}

// ---------- launch ----------
extern "C" void kernel_launch(void* const* d_in, const int* in_sizes, int n_in,
                              void* d_out, int out_size, void* d_ws, size_t ws_size,
                              hipStream_t stream) {
  const float* x      = (const float*)d_in[0];
  const float* qkv_w  = (const float*)d_in[1];
  const float* q_g    = (const float*)d_in[2];
  const float* q_b    = (const float*)d_in[3];
  const float* k_g    = (const float*)d_in[4];
  const float* k_b    = (const float*)d_in[5];
  const float* proj_w = (const float*)d_in[6];
  const float* proj_b = (const float*)d_in[7];
  float* out = (float*)d_out;

  char* ws = (char*)d_ws;
  // byte offsets (all 256-aligned)
  u16* xb     = (u16*)(ws + 0);                       //  8 MB  [4096][1024]
  u16* wqkvT  = (u16*)(ws + 8388608);                 //  6 MB  [3072][1024]
  u16* wprojT = (u16*)(ws + 14680064);                //  2 MB  [1024][1024]
  u16* Qh     = (u16*)(ws + 16777216);                //  8 MB  [32][2048][64]
  u16* Kh     = (u16*)(ws + 25165824);                //  8 MB
  u16* Vh     = (u16*)(ws + 33554432);                //  8 MB
  u16* Vt     = (u16*)(ws + 41943040);                //  8 MB  [32][64][2048]
  u16* attnO  = xb;                                   // reuse (xb dead after QKV GEMM)

  k_cast_bf16<<<4096, 256, 0, stream>>>(x, xb, (BN_ * C_) / 4);
  k_transpose_cast<<<dim3(96, 32), dim3(32, 8), 0, stream>>>(qkv_w, wqkvT, C_, 3 * C_);
  k_transpose_cast<<<dim3(32, 32), dim3(32, 8), 0, stream>>>(proj_w, wprojT, C_, C_);
  k_gemm_qkv_ln<<<dim3(24, 32), 256, 0, stream>>>(xb, wqkvT, q_g, q_b, k_g, k_b, Qh, Kh, Vh);
  k_transpose_v<<<dim3(32, 32), dim3(64, 8), 0, stream>>>(Vh, Vt);
  k_attn<<<dim3(16, 32), 512, 0, stream>>>(Qh, Kh, Vt, attnO);
  k_gemm_proj<<<dim3(8, 32), 256, 0, stream>>>(attnO, wprojT, out, proj_b, BN_, C_, C_);
}